// Round 1
// baseline (943.989 us; speedup 1.0000x reference)
//
#include <hip/hip_runtime.h>
#include <stdint.h>

// ---------------------------------------------------------------------------
// MultiHeadAttention: out = softmax(mask((X Wq^T)(X Wk^T)^T * E^-0.5)) (X Wv^T) Wo^T + bo
// N=4, L=2048, E=2048, H=16, D=128.  All GEMMs in bf16 MFMA (16x16x32), softmax f32.
// Workspace layout (needs 160 MB):
//   [0,32MB)    Wq_b, Wk_b, Wv_b, Wo_b  (bf16, 8MB each)
//   [32,128MB)  q_proj, k_proj, v_proj  (bf16, 32MB each, [N*L][E])
//   [128,160MB) attn output O          (bf16, 32MB, [N*L][E])
// ---------------------------------------------------------------------------

typedef __bf16 bf16;
typedef __bf16 bf16x4 __attribute__((ext_vector_type(4)));
typedef __bf16 bf16x8 __attribute__((ext_vector_type(8)));
typedef float  f32x4  __attribute__((ext_vector_type(4)));

#define MFMA16(a, b, c) __builtin_amdgcn_mfma_f32_16x16x32_bf16(a, b, c, 0, 0, 0)

__device__ __forceinline__ void gload_lds16(const void* g, void* s) {
  // async global->LDS, 16B per lane; LDS dest = wave-uniform base + lane*16
  __builtin_amdgcn_global_load_lds(
      (const __attribute__((address_space(1))) void*)g,
      (__attribute__((address_space(3))) void*)s, 16, 0, 0);
}

// ---------------------------------------------------------------------------
// f32 -> bf16 conversion (weights)
// ---------------------------------------------------------------------------
__global__ __launch_bounds__(256) void cvt_bf16(const float* __restrict__ src,
                                                bf16* __restrict__ dst, long n) {
  long i = ((long)blockIdx.x * 256 + threadIdx.x) * 4;
  if (i < n) {
    f32x4 f = *(const f32x4*)(src + i);
    bf16x4 h = { (bf16)f.x, (bf16)f.y, (bf16)f.z, (bf16)f.w };
    *(bf16x4*)(dst + i) = h;
  }
}

// ---------------------------------------------------------------------------
// GEMM  C[M,N] = A[M,K] @ B[N,K]^T   (B^T layout: both operands row-major-K)
// 128x128 tile, BK=64, 256 threads = 4 waves (2x2), each wave 64x64 = 4x4 frags.
// A_F32: A is f32, reg-staged + converted to bf16 in LDS. Else bf16 via gload_lds.
// ---------------------------------------------------------------------------
template <int A_F32, int OUT_F32, int ADD_BIAS>
__global__ __launch_bounds__(256) void gemm_bt(const void* __restrict__ Ain,
                                               const bf16* __restrict__ B,
                                               void* __restrict__ Cout,
                                               const float* __restrict__ bias,
                                               int M, int N, int K) {
  constexpr int BM = 128, BN = 128, BK = 64;
  __shared__ bf16 At[BM * BK];  // [128][64], rows 128B, linear
  __shared__ bf16 Bt[BN * BK];
  const int t = threadIdx.x;
  const int l = t & 63;
  const int w = t >> 6;
  const int wr = w >> 1, wc = w & 1;
  const int l15 = l & 15, l4 = l >> 4;
  const long tm = (long)blockIdx.y * BM;
  const long tn = (long)blockIdx.x * BN;

  f32x4 acc[4][4];
#pragma unroll
  for (int i = 0; i < 4; ++i)
#pragma unroll
    for (int j = 0; j < 4; ++j) acc[i][j] = (f32x4){0.f, 0.f, 0.f, 0.f};

  const bf16* Ab = (const bf16*)Ain;
  const float* Af = (const float*)Ain;

  for (int k0 = 0; k0 < K; k0 += BK) {
    // ---- stage B (bf16) via global_load_lds: 16 chunks x 1024B
#pragma unroll
    for (int i = 0; i < 4; ++i) {
      int chunk = w * 4 + i;
      int row = chunk * 8 + (l >> 3);
      gload_lds16(B + (tn + row) * (long)K + k0 + (l & 7) * 8, Bt + chunk * 512);
    }
    // ---- stage A
    if constexpr (A_F32) {
      // reg-stage: load f32, cvt, ds_write 8B
#pragma unroll
      for (int i = 0; i < 8; ++i) {
        int u = t + 256 * i;   // 0..2047 float4-units
        int row = u >> 4;      // 16 float4 per 64-wide row
        int kq = u & 15;
        f32x4 fv = *(const f32x4*)(Af + (tm + row) * (long)K + k0 + kq * 4);
        bf16x4 hv = { (bf16)fv.x, (bf16)fv.y, (bf16)fv.z, (bf16)fv.w };
        *(bf16x4*)(At + row * BK + kq * 4) = hv;
      }
    } else {
#pragma unroll
      for (int i = 0; i < 4; ++i) {
        int chunk = w * 4 + i;
        int row = chunk * 8 + (l >> 3);
        gload_lds16(Ab + (tm + row) * (long)K + k0 + (l & 7) * 8, At + chunk * 512);
      }
    }
    __syncthreads();
    // ---- compute: 2 k-steps of 32, 16 MFMA each
#pragma unroll
    for (int kk = 0; kk < 2; ++kk) {
      bf16x8 af[4], bfr[4];
#pragma unroll
      for (int mi = 0; mi < 4; ++mi)
        af[mi] = *(const bf16x8*)(At + (wr * 64 + mi * 16 + l15) * BK + kk * 32 + l4 * 8);
#pragma unroll
      for (int ni = 0; ni < 4; ++ni)
        bfr[ni] = *(const bf16x8*)(Bt + (wc * 64 + ni * 16 + l15) * BK + kk * 32 + l4 * 8);
#pragma unroll
      for (int mi = 0; mi < 4; ++mi)
#pragma unroll
        for (int ni = 0; ni < 4; ++ni)
          acc[mi][ni] = MFMA16(af[mi], bfr[ni], acc[mi][ni]);
    }
    __syncthreads();
  }

  // ---- epilogue: D layout col=l&15, row=4*(l>>4)+r
#pragma unroll
  for (int mi = 0; mi < 4; ++mi) {
#pragma unroll
    for (int ni = 0; ni < 4; ++ni) {
      long col = tn + wc * 64 + ni * 16 + l15;
      long row = tm + wr * 64 + mi * 16 + l4 * 4;
#pragma unroll
      for (int r = 0; r < 4; ++r) {
        float v = acc[mi][ni][r];
        if constexpr (OUT_F32) {
          if constexpr (ADD_BIAS) v += bias[col];
          ((float*)Cout)[(row + r) * (long)N + col] = v;
        } else {
          ((bf16*)Cout)[(row + r) * (long)N + col] = (bf16)v;
        }
      }
    }
  }
}

// ---------------------------------------------------------------------------
// Flash attention fwd. grid = (L/128, N*H), 256 threads = 4 waves.
// Wave w owns 32 q-rows. Q in registers; K,V^T staged in LDS per 64-key tile;
// P (bf16) round-trips via LDS (same-wave rows only). Online softmax in f32.
// ---------------------------------------------------------------------------
__global__ __launch_bounds__(256) void attn_fwd(const bf16* __restrict__ Qp,
                                                const bf16* __restrict__ Kp,
                                                const bf16* __restrict__ Vp,
                                                const int* __restrict__ mask,
                                                bf16* __restrict__ Op) {
  constexpr int L = 2048, E = 2048, D = 128, KVB = 64;
  __shared__ bf16 Kt[KVB * D];    // [j][d]  16KB, rows 256B
  __shared__ bf16 VT[D * KVB];    // [d][j]  16KB, rows 128B
  __shared__ bf16 Pt[128 * 72];   // [q][j]  stride 72 (pad) 18KB
  const int t = threadIdx.x, l = t & 63, w = t >> 6;
  const int l15 = l & 15, l4 = l >> 4;
  const int n = blockIdx.y >> 4, h = blockIdx.y & 15;
  const int q0 = blockIdx.x * 128;
  const int wq = w * 32;
  const float scale = 0.022097086912079608f;  // E^-0.5

  const bf16* Qb = Qp + ((long)n * L + q0) * E + h * D;
  const bf16* Kb = Kp + (long)n * L * E + h * D;
  const bf16* Vb = Vp + (long)n * L * E + h * D;
  const int* mb = mask + n * L;

  // Q fragments in registers: rows wq..wq+31, all 128 d
  bf16x8 qf[2][4];
#pragma unroll
  for (int mi = 0; mi < 2; ++mi)
#pragma unroll
    for (int kk = 0; kk < 4; ++kk)
      qf[mi][kk] = *(const bf16x8*)(Qb + (long)(wq + mi * 16 + l15) * E + kk * 32 + l4 * 8);

  f32x4 o[2][8];
#pragma unroll
  for (int mi = 0; mi < 2; ++mi)
#pragma unroll
    for (int ni = 0; ni < 8; ++ni) o[mi][ni] = (f32x4){0.f, 0.f, 0.f, 0.f};
  float mreg[2][4], lreg[2][4];
#pragma unroll
  for (int mi = 0; mi < 2; ++mi)
#pragma unroll
    for (int r = 0; r < 4; ++r) { mreg[mi][r] = -1e20f; lreg[mi][r] = 0.f; }

  const int vd0 = (t >> 4) * 8;  // d-range this thread transposes
  const int vj0 = (t & 15) * 4;  // j-range (4 rows)

  for (int kv = 0; kv < L; kv += KVB) {
    // ---- stage K tile (gload_lds, linear)
#pragma unroll
    for (int i = 0; i < 4; ++i) {
      int chunk = w * 4 + i;
      int row = chunk * 4 + l4;
      gload_lds16(Kb + (long)(kv + row) * E + l15 * 8, Kt + chunk * 512);
    }
    // ---- stage V transposed: reg load 4 rows x 8 d, write 8B packed columns
    bf16x8 vr[4];
#pragma unroll
    for (int r = 0; r < 4; ++r)
      vr[r] = *(const bf16x8*)(Vb + (long)(kv + vj0 + r) * E + vd0);
#pragma unroll
    for (int i = 0; i < 8; ++i) {
      bf16x4 pk = { vr[0][i], vr[1][i], vr[2][i], vr[3][i] };
      *(bf16x4*)(VT + (vd0 + i) * KVB + vj0) = pk;
    }
    __syncthreads();

    // ---- S = Q K^T (wave's 32 q-rows x 64 keys)
    f32x4 s[2][4];
#pragma unroll
    for (int mi = 0; mi < 2; ++mi)
#pragma unroll
      for (int ni = 0; ni < 4; ++ni) s[mi][ni] = (f32x4){0.f, 0.f, 0.f, 0.f};
#pragma unroll
    for (int kk = 0; kk < 4; ++kk) {
      bf16x8 kf[4];
#pragma unroll
      for (int ni = 0; ni < 4; ++ni)
        kf[ni] = *(const bf16x8*)(Kt + (ni * 16 + l15) * D + kk * 32 + l4 * 8);
#pragma unroll
      for (int mi = 0; mi < 2; ++mi)
#pragma unroll
        for (int ni = 0; ni < 4; ++ni)
          s[mi][ni] = MFMA16(qf[mi][kk], kf[ni], s[mi][ni]);
    }

    int mk[4];
#pragma unroll
    for (int ni = 0; ni < 4; ++ni) mk[ni] = mb[kv + ni * 16 + l15];

    // ---- online softmax (rows live across 16-lane groups; shfl_xor 1,2,4,8)
#pragma unroll
    for (int mi = 0; mi < 2; ++mi) {
#pragma unroll
      for (int r = 0; r < 4; ++r) {
        float sv[4];
        float vmax = -1e20f;
#pragma unroll
        for (int ni = 0; ni < 4; ++ni) {
          float x = s[mi][ni][r] * scale;
          x = (mk[ni] == 0) ? -1e20f : x;
          sv[ni] = x;
          vmax = fmaxf(vmax, x);
        }
#pragma unroll
        for (int d = 1; d < 16; d <<= 1) vmax = fmaxf(vmax, __shfl_xor(vmax, d));
        float mold = mreg[mi][r];
        float mnew = fmaxf(mold, vmax);
        float corr = __expf(mold - mnew);
        float rsum = 0.f;
        int qrow = wq + mi * 16 + l4 * 4 + r;
#pragma unroll
        for (int ni = 0; ni < 4; ++ni) {
          float p = __expf(sv[ni] - mnew);
          rsum += p;
          Pt[qrow * 72 + ni * 16 + l15] = (bf16)p;
        }
#pragma unroll
        for (int d = 1; d < 16; d <<= 1) rsum += __shfl_xor(rsum, d);
        lreg[mi][r] = lreg[mi][r] * corr + rsum;
        mreg[mi][r] = mnew;
#pragma unroll
        for (int ni = 0; ni < 8; ++ni) o[mi][ni][r] *= corr;
      }
    }

    // ---- O += P V (P rows were written by this same wave: in-order DS, no barrier)
#pragma unroll
    for (int kk = 0; kk < 2; ++kk) {
      bf16x8 pa[2], vb[8];
#pragma unroll
      for (int mi = 0; mi < 2; ++mi)
        pa[mi] = *(const bf16x8*)(Pt + (wq + mi * 16 + l15) * 72 + kk * 32 + l4 * 8);
#pragma unroll
      for (int ni = 0; ni < 8; ++ni)
        vb[ni] = *(const bf16x8*)(VT + (ni * 16 + l15) * KVB + kk * 32 + l4 * 8);
#pragma unroll
      for (int mi = 0; mi < 2; ++mi)
#pragma unroll
        for (int ni = 0; ni < 8; ++ni)
          o[mi][ni] = MFMA16(pa[mi], vb[ni], o[mi][ni]);
    }
    __syncthreads();  // protect Kt/VT before next stage
  }

  // ---- epilogue: O / l, write bf16
#pragma unroll
  for (int mi = 0; mi < 2; ++mi) {
#pragma unroll
    for (int r = 0; r < 4; ++r) {
      float inv = 1.f / lreg[mi][r];
      long grow = (long)n * L + q0 + wq + mi * 16 + l4 * 4 + r;
#pragma unroll
      for (int ni = 0; ni < 8; ++ni)
        Op[grow * E + h * D + ni * 16 + l15] = (bf16)(o[mi][ni][r] * inv);
    }
  }
}

// ---------------------------------------------------------------------------
extern "C" void kernel_launch(void* const* d_in, const int* in_sizes, int n_in,
                              void* d_out, int out_size, void* d_ws, size_t ws_size,
                              hipStream_t stream) {
  (void)in_sizes; (void)n_in; (void)out_size; (void)ws_size;
  const float* query = (const float*)d_in[0];
  const float* keys  = (const float*)d_in[1];
  const float* values= (const float*)d_in[2];
  const int*   mask  = (const int*)d_in[3];
  const float* Wq = (const float*)d_in[4];
  const float* Wk = (const float*)d_in[5];
  const float* Wv = (const float*)d_in[6];
  const float* Wo = (const float*)d_in[7];
  const float* bo = (const float*)d_in[8];
  float* out = (float*)d_out;

  const int N = 4, L = 2048, E = 2048;
  const int M = N * L;  // 8192
  const long EE = (long)E * E;

  bf16* Wqb = (bf16*)d_ws;
  bf16* Wkb = Wqb + EE;
  bf16* Wvb = Wkb + EE;
  bf16* Wob = Wvb + EE;
  bf16* qp  = Wob + EE;
  bf16* kp  = qp + (long)M * E;
  bf16* vp  = kp + (long)M * E;
  bf16* op  = vp + (long)M * E;

  // 1) weights -> bf16
  int cb = (int)(EE / 4 / 256);  // 4096 blocks
  cvt_bf16<<<cb, 256, 0, stream>>>(Wq, Wqb, EE);
  cvt_bf16<<<cb, 256, 0, stream>>>(Wk, Wkb, EE);
  cvt_bf16<<<cb, 256, 0, stream>>>(Wv, Wvb, EE);
  cvt_bf16<<<cb, 256, 0, stream>>>(Wo, Wob, EE);

  // 2) projections: q = X Wq^T etc. (A f32 reg-staged, C bf16)
  dim3 gg(E / 128, M / 128);  // (16, 64)
  gemm_bt<1, 0, 0><<<gg, 256, 0, stream>>>(query,  Wqb, qp, nullptr, M, E, E);
  gemm_bt<1, 0, 0><<<gg, 256, 0, stream>>>(keys,   Wkb, kp, nullptr, M, E, E);
  gemm_bt<1, 0, 0><<<gg, 256, 0, stream>>>(values, Wvb, vp, nullptr, M, E, E);

  // 3) attention
  attn_fwd<<<dim3(L / 128, N * 16), 256, 0, stream>>>(qp, kp, vp, mask, op);

  // 4) output projection + bias (A bf16 via gload_lds, C f32)
  gemm_bt<0, 1, 1><<<gg, 256, 0, stream>>>(op, Wob, out, bo, M, E, E);
}

// Round 2
// 861.962 us; speedup vs baseline: 1.0952x; 1.0952x over previous
//
#include <hip/hip_runtime.h>
#include <stdint.h>

// ---------------------------------------------------------------------------
// MultiHeadAttention: out = softmax(mask((X Wq^T)(X Wk^T)^T * E^-0.5)) (X Wv^T) Wo^T + bo
// N=4, L=2048, E=2048, H=16, D=128.  All GEMMs in bf16 MFMA (16x16x32), softmax f32.
// Workspace layout (160 MB):
//   [0,32MB)    Wq_b, Wk_b, Wv_b, Wo_b  (bf16, 8MB each)
//   [32,128MB)  q_proj, k_proj, v_proj  (bf16, 32MB each, [N*L][E])
//   [128,160MB) X_bf16 staging (during projections) / attn output O (after)
// ---------------------------------------------------------------------------

typedef __bf16 bf16;
typedef __bf16 bf16x4 __attribute__((ext_vector_type(4)));
typedef __bf16 bf16x8 __attribute__((ext_vector_type(8)));
typedef float  f32x4  __attribute__((ext_vector_type(4)));

#define MFMA16(a, b, c) __builtin_amdgcn_mfma_f32_16x16x32_bf16(a, b, c, 0, 0, 0)

__device__ __forceinline__ void gload_lds16(const void* g, void* s) {
  // async global->LDS, 16B per lane; LDS dest = wave-uniform base + lane*16
  __builtin_amdgcn_global_load_lds(
      (const __attribute__((address_space(1))) void*)g,
      (__attribute__((address_space(3))) void*)s, 16, 0, 0);
}

// ---------------------------------------------------------------------------
// f32 -> bf16 conversion
// ---------------------------------------------------------------------------
__global__ __launch_bounds__(256) void cvt_bf16(const float* __restrict__ src,
                                                bf16* __restrict__ dst, long n) {
  long i = ((long)blockIdx.x * 256 + threadIdx.x) * 4;
  if (i < n) {
    f32x4 f = *(const f32x4*)(src + i);
    bf16x4 h = { (bf16)f.x, (bf16)f.y, (bf16)f.z, (bf16)f.w };
    *(bf16x4*)(dst + i) = h;
  }
}

// ---------------------------------------------------------------------------
// GEMM  C[M,N] = A[M,K] @ B[N,K]^T   (both operands bf16, row-major-K)
// 128x128 tile, BK=64, 256 threads = 4 waves (2x2), each wave 64x64 = 4x4 frags.
// ---------------------------------------------------------------------------
template <int OUT_F32, int ADD_BIAS>
__global__ __launch_bounds__(256) void gemm_bt(const bf16* __restrict__ A,
                                               const bf16* __restrict__ B,
                                               void* __restrict__ Cout,
                                               const float* __restrict__ bias,
                                               int M, int N, int K) {
  constexpr int BM = 128, BN = 128, BK = 64;
  __shared__ bf16 At[BM * BK];  // [128][64], rows 128B, linear
  __shared__ bf16 Bt[BN * BK];
  const int t = threadIdx.x;
  const int l = t & 63;
  const int w = t >> 6;
  const int wr = w >> 1, wc = w & 1;
  const int l15 = l & 15, l4 = l >> 4;
  const long tm = (long)blockIdx.y * BM;
  const long tn = (long)blockIdx.x * BN;

  f32x4 acc[4][4];
#pragma unroll
  for (int i = 0; i < 4; ++i)
#pragma unroll
    for (int j = 0; j < 4; ++j) acc[i][j] = (f32x4){0.f, 0.f, 0.f, 0.f};

  for (int k0 = 0; k0 < K; k0 += BK) {
#pragma unroll
    for (int i = 0; i < 4; ++i) {
      int chunk = w * 4 + i;
      int row = chunk * 8 + (l >> 3);
      gload_lds16(B + (tn + row) * (long)K + k0 + (l & 7) * 8, Bt + chunk * 512);
    }
#pragma unroll
    for (int i = 0; i < 4; ++i) {
      int chunk = w * 4 + i;
      int row = chunk * 8 + (l >> 3);
      gload_lds16(A + (tm + row) * (long)K + k0 + (l & 7) * 8, At + chunk * 512);
    }
    __syncthreads();
#pragma unroll
    for (int kk = 0; kk < 2; ++kk) {
      bf16x8 af[4], bfr[4];
#pragma unroll
      for (int mi = 0; mi < 4; ++mi)
        af[mi] = *(const bf16x8*)(At + (wr * 64 + mi * 16 + l15) * BK + kk * 32 + l4 * 8);
#pragma unroll
      for (int ni = 0; ni < 4; ++ni)
        bfr[ni] = *(const bf16x8*)(Bt + (wc * 64 + ni * 16 + l15) * BK + kk * 32 + l4 * 8);
#pragma unroll
      for (int mi = 0; mi < 4; ++mi)
#pragma unroll
        for (int ni = 0; ni < 4; ++ni)
          acc[mi][ni] = MFMA16(af[mi], bfr[ni], acc[mi][ni]);
    }
    __syncthreads();
  }

  // D layout: col=l&15, row=4*(l>>4)+r
#pragma unroll
  for (int mi = 0; mi < 4; ++mi) {
#pragma unroll
    for (int ni = 0; ni < 4; ++ni) {
      long col = tn + wc * 64 + ni * 16 + l15;
      long row = tm + wr * 64 + mi * 16 + l4 * 4;
#pragma unroll
      for (int r = 0; r < 4; ++r) {
        float v = acc[mi][ni][r];
        if constexpr (OUT_F32) {
          if constexpr (ADD_BIAS) v += bias[col];
          ((float*)Cout)[(row + r) * (long)N + col] = v;
        } else {
          ((bf16*)Cout)[(row + r) * (long)N + col] = (bf16)v;
        }
      }
    }
  }
}

// ---------------------------------------------------------------------------
// Flash attention fwd. grid = (L/128, N*H), 256 threads = 4 waves.
// Wave w owns 32 q-rows. Q in regs. K,V^T in LDS, XOR-swizzled (T2):
//   K: linear LDS dest (global_load_lds) + pre-swizzled GLOBAL source; read
//      with slot16 ^= (row&7)   [rule #21: both-sides-or-neither]
//   V^T: reg-staged transpose, swizzle on write and read (slot16 ^= d&7)
// QK^T computed SWAPPED: s = mfma(K,Q) -> S^T, so each thread owns 16
// j-values of one q-row: softmax row-reduce = 2 shfls, P written as b64 packs.
// T13 defer-max (THR=8). Masked j via additive -1e20 bias (fma).
// ---------------------------------------------------------------------------
__global__ __launch_bounds__(256) void attn_fwd(const bf16* __restrict__ Qp,
                                                const bf16* __restrict__ Kp,
                                                const bf16* __restrict__ Vp,
                                                const int* __restrict__ mask,
                                                bf16* __restrict__ Op) {
  constexpr int L = 2048, E = 2048, D = 128, KVB = 64;
  __shared__ bf16 Kt[KVB * D];    // [j][d]  16KB, 256B rows, 16 slots of 16B
  __shared__ bf16 VT[D * KVB];    // [d][j]  16KB, 128B rows, 8 slots of 16B
  __shared__ bf16 Pt[128 * 72];   // [q][j]  stride 72 (pad) 18KB
  const int t = threadIdx.x, l = t & 63, w = t >> 6;
  const int l15 = l & 15, l4 = l >> 4;
  const int n = blockIdx.y >> 4, h = blockIdx.y & 15;
  const int q0 = blockIdx.x * 128;
  const int wq = w * 32;
  const float scale = 0.022097086912079608f;  // E^-0.5

  const bf16* Qb = Qp + ((long)n * L + q0) * E + h * D;
  const bf16* Kb = Kp + (long)n * L * E + h * D;
  const bf16* Vb = Vp + (long)n * L * E + h * D;
  const int* mb = mask + n * L;

  // Q fragments (MFMA B-operand): rows wq+mi*16+l15, cols kk*32+l4*8
  bf16x8 qf[2][4];
#pragma unroll
  for (int mi = 0; mi < 2; ++mi)
#pragma unroll
    for (int kk = 0; kk < 4; ++kk)
      qf[mi][kk] = *(const bf16x8*)(Qb + (long)(wq + mi * 16 + l15) * E + kk * 32 + l4 * 8);

  f32x4 o[2][8];
#pragma unroll
  for (int mi = 0; mi < 2; ++mi)
#pragma unroll
    for (int ni = 0; ni < 8; ++ni) o[mi][ni] = (f32x4){0.f, 0.f, 0.f, 0.f};
  float mreg[2] = {-1e20f, -1e20f};
  float lreg[2] = {0.f, 0.f};

  const int vd0 = (t >> 4) * 8;  // d-range this thread transposes (8 rows of VT)
  const int vj0 = (t & 15) * 4;  // j-range (4 columns)

  for (int kv = 0; kv < L; kv += KVB) {
    // ---- stage K: linear LDS dest, PRE-SWIZZLED global source
#pragma unroll
    for (int i = 0; i < 4; ++i) {
      int chunk = w * 4 + i;
      int row = chunk * 4 + l4;                 // LDS row this lane fills
      int srcslot = l15 ^ (row & 7);            // inverse (=same) XOR swizzle
      gload_lds16(Kb + (long)(kv + row) * E + srcslot * 8, Kt + chunk * 512);
    }
    // ---- stage V transposed, swizzled write: elem ^= (d&7)<<3
    bf16x8 vr[4];
#pragma unroll
    for (int r = 0; r < 4; ++r)
      vr[r] = *(const bf16x8*)(Vb + (long)(kv + vj0 + r) * E + vd0);
#pragma unroll
    for (int i = 0; i < 8; ++i) {
      int d = vd0 + i;
      bf16x4 pk = { vr[0][i], vr[1][i], vr[2][i], vr[3][i] };
      *(bf16x4*)(VT + d * KVB + (vj0 ^ ((d & 7) << 3))) = pk;
    }
    __syncthreads();

    // ---- S^T = K Q^T: s[mi][ni] holds S^T[j = ni*16+l4*4+r][q = l15]
    f32x4 s[2][4];
#pragma unroll
    for (int mi = 0; mi < 2; ++mi)
#pragma unroll
      for (int ni = 0; ni < 4; ++ni) s[mi][ni] = (f32x4){0.f, 0.f, 0.f, 0.f};
#pragma unroll
    for (int kk = 0; kk < 4; ++kk) {
      bf16x8 kf[4];
#pragma unroll
      for (int ni = 0; ni < 4; ++ni) {
        int row = ni * 16 + l15;
        int slot = (kk * 4 + l4) ^ (l15 & 7);   // swizzled 16B slot
        kf[ni] = *(const bf16x8*)(Kt + row * D + slot * 8);
      }
#pragma unroll
      for (int mi = 0; mi < 2; ++mi)
#pragma unroll
        for (int ni = 0; ni < 4; ++ni)
          s[mi][ni] = MFMA16(kf[ni], qf[mi][kk], s[mi][ni]);
    }

    // ---- mask bias (additive), int4 loads; same for both mi
    int4 mv[4];
#pragma unroll
    for (int ni = 0; ni < 4; ++ni)
      mv[ni] = *(const int4*)(mb + kv + ni * 16 + l4 * 4);
    float fb[4][4];
#pragma unroll
    for (int ni = 0; ni < 4; ++ni) {
      const int* mp = (const int*)&mv[ni];
#pragma unroll
      for (int r = 0; r < 4; ++r) fb[ni][r] = mp[r] ? 0.f : -1e20f;
    }

    // ---- online softmax, thread-local row (q = l15 part); T13 defer-max
    bool need[2];
    float corr[2];
#pragma unroll
    for (int mi = 0; mi < 2; ++mi) {
      float vmax = -1e20f;
#pragma unroll
      for (int ni = 0; ni < 4; ++ni)
#pragma unroll
        for (int r = 0; r < 4; ++r) {
          float xv = fmaf(s[mi][ni][r], scale, fb[ni][r]);
          s[mi][ni][r] = xv;
          vmax = fmaxf(vmax, xv);
        }
      vmax = fmaxf(vmax, __shfl_xor(vmax, 16));
      vmax = fmaxf(vmax, __shfl_xor(vmax, 32));
      bool nd = vmax > mreg[mi] + 8.0f;
      float mn = nd ? vmax : mreg[mi];
      corr[mi] = nd ? __expf(mreg[mi] - vmax) : 1.0f;
      need[mi] = nd;
      mreg[mi] = mn;
      float rsum = 0.f;
#pragma unroll
      for (int ni = 0; ni < 4; ++ni) {
        bf16x4 pk;
#pragma unroll
        for (int r = 0; r < 4; ++r) {
          float p = __expf(s[mi][ni][r] - mn);
          rsum += p;
          pk[r] = (bf16)p;
        }
        *(bf16x4*)(Pt + (wq + mi * 16 + l15) * 72 + ni * 16 + l4 * 4) = pk;
      }
      rsum += __shfl_xor(rsum, 16);
      rsum += __shfl_xor(rsum, 32);
      lreg[mi] = lreg[mi] * corr[mi] + rsum;
    }
    // rare: redistribute corr (row q held at lane l15=q) to o-rows (l4*4+r)
    if (__any(need[0] || need[1])) {
#pragma unroll
      for (int mi = 0; mi < 2; ++mi) {
#pragma unroll
        for (int r = 0; r < 4; ++r) {
          float cr = __shfl(corr[mi], (l >> 4) * 20 + r);
#pragma unroll
          for (int ni = 0; ni < 8; ++ni) o[mi][ni][r] *= cr;
        }
      }
    }

    // ---- O += P V  (Pt rows written by this same wave: in-order DS)
#pragma unroll
    for (int kk = 0; kk < 2; ++kk) {
      bf16x8 pa[2], vb[8];
#pragma unroll
      for (int mi = 0; mi < 2; ++mi)
        pa[mi] = *(const bf16x8*)(Pt + (wq + mi * 16 + l15) * 72 + kk * 32 + l4 * 8);
#pragma unroll
      for (int ni = 0; ni < 8; ++ni) {
        int d = ni * 16 + l15;
        int col = (kk * 32 + l4 * 8) ^ ((d & 7) << 3);  // swizzled
        vb[ni] = *(const bf16x8*)(VT + d * KVB + col);
      }
#pragma unroll
      for (int mi = 0; mi < 2; ++mi)
#pragma unroll
        for (int ni = 0; ni < 8; ++ni)
          o[mi][ni] = MFMA16(pa[mi], vb[ni], o[mi][ni]);
    }
    __syncthreads();  // protect Kt/VT before next stage
  }

  // ---- epilogue: redistribute 1/l (held at lane l15=q) to o-rows, write bf16
  float inv[2];
#pragma unroll
  for (int mi = 0; mi < 2; ++mi) inv[mi] = 1.f / lreg[mi];
#pragma unroll
  for (int mi = 0; mi < 2; ++mi) {
#pragma unroll
    for (int r = 0; r < 4; ++r) {
      float iv = __shfl(inv[mi], (l >> 4) * 20 + r);
      long grow = (long)n * L + q0 + wq + mi * 16 + l4 * 4 + r;
#pragma unroll
      for (int ni = 0; ni < 8; ++ni)
        Op[grow * E + h * D + ni * 16 + l15] = (bf16)(o[mi][ni][r] * iv);
    }
  }
}

// ---------------------------------------------------------------------------
extern "C" void kernel_launch(void* const* d_in, const int* in_sizes, int n_in,
                              void* d_out, int out_size, void* d_ws, size_t ws_size,
                              hipStream_t stream) {
  (void)in_sizes; (void)n_in; (void)out_size; (void)ws_size;
  const float* query = (const float*)d_in[0];
  const float* keys  = (const float*)d_in[1];
  const float* values= (const float*)d_in[2];
  const int*   mask  = (const int*)d_in[3];
  const float* Wq = (const float*)d_in[4];
  const float* Wk = (const float*)d_in[5];
  const float* Wv = (const float*)d_in[6];
  const float* Wo = (const float*)d_in[7];
  const float* bo = (const float*)d_in[8];
  float* out = (float*)d_out;

  const int N = 4, L = 2048, E = 2048;
  const int M = N * L;  // 8192
  const long EE = (long)E * E;
  const long ME = (long)M * E;

  bf16* Wqb = (bf16*)d_ws;
  bf16* Wkb = Wqb + EE;
  bf16* Wvb = Wkb + EE;
  bf16* Wob = Wvb + EE;
  bf16* qp  = Wob + EE;
  bf16* kp  = qp + ME;
  bf16* vp  = kp + ME;
  bf16* op  = vp + ME;   // also used as bf16 X staging during projections
  bf16* xb  = op;

  // 1) weights -> bf16
  int cbw = (int)(EE / 4 / 256);
  cvt_bf16<<<cbw, 256, 0, stream>>>(Wq, Wqb, EE);
  cvt_bf16<<<cbw, 256, 0, stream>>>(Wk, Wkb, EE);
  cvt_bf16<<<cbw, 256, 0, stream>>>(Wv, Wvb, EE);
  cvt_bf16<<<cbw, 256, 0, stream>>>(Wo, Wob, EE);

  // 2) projections: cvt activation -> bf16 (staging in op region), then GEMM
  int cba = (int)(ME / 4 / 256);
  dim3 gg(E / 128, M / 128);  // (16, 64)
  cvt_bf16<<<cba, 256, 0, stream>>>(query, xb, ME);
  gemm_bt<0, 0><<<gg, 256, 0, stream>>>(xb, Wqb, qp, nullptr, M, E, E);
  cvt_bf16<<<cba, 256, 0, stream>>>(keys, xb, ME);
  gemm_bt<0, 0><<<gg, 256, 0, stream>>>(xb, Wkb, kp, nullptr, M, E, E);
  cvt_bf16<<<cba, 256, 0, stream>>>(values, xb, ME);
  gemm_bt<0, 0><<<gg, 256, 0, stream>>>(xb, Wvb, vp, nullptr, M, E, E);

  // 3) attention (writes op; xb staging is dead by now)
  attn_fwd<<<dim3(L / 128, N * 16), 256, 0, stream>>>(qp, kp, vp, mask, op);

  // 4) output projection + bias
  gemm_bt<1, 1><<<gg, 256, 0, stream>>>(op, Wob, out, bo, M, E, E);
}

// Round 3
// 668.567 us; speedup vs baseline: 1.4120x; 1.2893x over previous
//
#include <hip/hip_runtime.h>
#include <stdint.h>

// ---------------------------------------------------------------------------
// MultiHeadAttention: out = softmax(mask((X Wq^T)(X Wk^T)^T * E^-0.5)) (X Wv^T) Wo^T + bo
// N=4, L=2048, E=2048, H=16, D=128.  bf16 MFMA GEMMs, f32 softmax.
// KEY OPT: mask is per-(n,key); masked keys contribute exactly 0 after softmax.
// Compact unmasked key indices per n (~50%) -> K/V projections + attention run
// on ~half the keys. Attention tail-tile masks j>=cnt with -1e20.
// Workspace (~128.04 MB):
//   [0,32MB)     Wq_b, Wk_b, Wv_b, Wo_b (bf16, 8MB each)
//   [32,64MB)    qp  (bf16 [8192][2048])  -- attn output aliases this
//   [64,96MB)    kp  (compacted K proj)
//   [96,128MB)   vp  (compacted V proj)
//   [128MB..)    idx (int[4][2048]), cnts (int[8]: cnt[4], cntp128[4])
// ---------------------------------------------------------------------------

typedef __bf16 bf16;
typedef __bf16 bf16x4 __attribute__((ext_vector_type(4)));
typedef __bf16 bf16x8 __attribute__((ext_vector_type(8)));
typedef float  f32x4  __attribute__((ext_vector_type(4)));

#define MFMA16(a, b, c) __builtin_amdgcn_mfma_f32_16x16x32_bf16(a, b, c, 0, 0, 0)

__device__ __forceinline__ void gload_lds16(const void* g, void* s) {
  __builtin_amdgcn_global_load_lds(
      (const __attribute__((address_space(1))) void*)g,
      (__attribute__((address_space(3))) void*)s, 16, 0, 0);
}

// ---------------------------------------------------------------------------
__global__ __launch_bounds__(256) void cvt_bf16(const float* __restrict__ src,
                                                bf16* __restrict__ dst, long n) {
  long i = ((long)blockIdx.x * 256 + threadIdx.x) * 4;
  if (i < n) {
    f32x4 f = *(const f32x4*)(src + i);
    bf16x4 h = { (bf16)f.x, (bf16)f.y, (bf16)f.z, (bf16)f.w };
    *(bf16x4*)(dst + i) = h;
  }
}

// ---------------------------------------------------------------------------
// Per-n compaction of mask==1 indices. grid = 4 blocks x 256 threads.
// idx[n][0..cnt) = positions of unmasked keys; [cnt..2048) = 2047 (pad, safe).
// cnts[n] = cnt, cnts[4+n] = roundup128(cnt).
// ---------------------------------------------------------------------------
__global__ __launch_bounds__(256) void mask_compact(const int* __restrict__ mask,
                                                    int* __restrict__ idx,
                                                    int* __restrict__ cnts) {
  const int n = blockIdx.x;
  const int t = threadIdx.x, l = t & 63, w = t >> 6;
  const int* m = mask + n * 2048;
  __shared__ int wtot[4];
  int f[8], tt = 0;
  const int base = t * 8;
#pragma unroll
  for (int i = 0; i < 8; ++i) { f[i] = (m[base + i] != 0); tt += f[i]; }
  int sc = tt;  // inclusive scan over 64 lanes
#pragma unroll
  for (int d = 1; d < 64; d <<= 1) {
    int v = __shfl_up(sc, d);
    if (l >= d) sc += v;
  }
  if (l == 63) wtot[w] = sc;
  __syncthreads();
  int woff = 0;
#pragma unroll
  for (int i = 0; i < 4; ++i) if (i < w) woff += wtot[i];
  int off = woff + sc - tt;  // exclusive prefix for this thread
#pragma unroll
  for (int i = 0; i < 8; ++i)
    if (f[i]) { idx[n * 2048 + off] = base + i; ++off; }
  int total = wtot[0] + wtot[1] + wtot[2] + wtot[3];
  for (int p = total + t; p < 2048; p += 256) idx[n * 2048 + p] = 2047;
  if (t == 0) { cnts[n] = total; cnts[4 + n] = (total + 127) & ~127; }
}

// ---------------------------------------------------------------------------
// GEMM  C[M,N] = A[M,K] @ B[N,K]^T.  128x128 tile, BK=64, 4 waves (2x2).
// AMODE: 0 = A bf16 via global_load_lds; 1 = A f32 reg-staged+cvt;
//        2 = A f32 gathered via idx (per-n), blocks past cntp128 early-exit.
// ---------------------------------------------------------------------------
template <int AMODE, int OUT_F32, int ADD_BIAS>
__global__ __launch_bounds__(256) void gemm_bt(const void* __restrict__ Ain,
                                               const bf16* __restrict__ B,
                                               void* __restrict__ Cout,
                                               const float* __restrict__ bias,
                                               const int* __restrict__ idx,
                                               const int* __restrict__ cnts,
                                               int M, int N, int K) {
  constexpr int BM = 128, BN = 128, BK = 64;
  __shared__ bf16 At[BM * BK];
  __shared__ bf16 Bt[BN * BK];
  const int t = threadIdx.x;
  const int l = t & 63;
  const int w = t >> 6;
  const int wr = w >> 1, wc = w & 1;
  const int l15 = l & 15, l4 = l >> 4;
  const long tm = (long)blockIdx.y * BM;
  const long tn = (long)blockIdx.x * BN;

  int ibase = 0;
  if constexpr (AMODE == 2) {
    int n = (int)(tm >> 11);
    if ((int)(tm & 2047) >= cnts[4 + n]) return;  // beyond padded count
    ibase = n * 2048 + (int)(tm & 2047);
  }

  f32x4 acc[4][4];
#pragma unroll
  for (int i = 0; i < 4; ++i)
#pragma unroll
    for (int j = 0; j < 4; ++j) acc[i][j] = (f32x4){0.f, 0.f, 0.f, 0.f};

  const bf16* Ab = (const bf16*)Ain;
  const float* Af = (const float*)Ain;

  for (int k0 = 0; k0 < K; k0 += BK) {
#pragma unroll
    for (int i = 0; i < 4; ++i) {
      int chunk = w * 4 + i;
      int row = chunk * 8 + (l >> 3);
      gload_lds16(B + (tn + row) * (long)K + k0 + (l & 7) * 8, Bt + chunk * 512);
    }
    if constexpr (AMODE == 0) {
#pragma unroll
      for (int i = 0; i < 4; ++i) {
        int chunk = w * 4 + i;
        int row = chunk * 8 + (l >> 3);
        gload_lds16(Ab + (tm + row) * (long)K + k0 + (l & 7) * 8, At + chunk * 512);
      }
    } else {
#pragma unroll
      for (int i = 0; i < 8; ++i) {
        int u = t + 256 * i;
        int row = u >> 4;
        int kq = u & 15;
        long grow;
        if constexpr (AMODE == 2)
          grow = (tm & ~2047L) + idx[ibase + row];
        else
          grow = tm + row;
        f32x4 fv = *(const f32x4*)(Af + grow * (long)K + k0 + kq * 4);
        bf16x4 hv = { (bf16)fv.x, (bf16)fv.y, (bf16)fv.z, (bf16)fv.w };
        *(bf16x4*)(At + row * BK + kq * 4) = hv;
      }
    }
    __syncthreads();
#pragma unroll
    for (int kk = 0; kk < 2; ++kk) {
      bf16x8 af[4], bfr[4];
#pragma unroll
      for (int mi = 0; mi < 4; ++mi)
        af[mi] = *(const bf16x8*)(At + (wr * 64 + mi * 16 + l15) * BK + kk * 32 + l4 * 8);
#pragma unroll
      for (int ni = 0; ni < 4; ++ni)
        bfr[ni] = *(const bf16x8*)(Bt + (wc * 64 + ni * 16 + l15) * BK + kk * 32 + l4 * 8);
#pragma unroll
      for (int mi = 0; mi < 4; ++mi)
#pragma unroll
        for (int ni = 0; ni < 4; ++ni)
          acc[mi][ni] = MFMA16(af[mi], bfr[ni], acc[mi][ni]);
    }
    __syncthreads();
  }

#pragma unroll
  for (int mi = 0; mi < 4; ++mi) {
#pragma unroll
    for (int ni = 0; ni < 4; ++ni) {
      long col = tn + wc * 64 + ni * 16 + l15;
      long row = tm + wr * 64 + mi * 16 + l4 * 4;
#pragma unroll
      for (int r = 0; r < 4; ++r) {
        float v = acc[mi][ni][r];
        if constexpr (OUT_F32) {
          if constexpr (ADD_BIAS) v += bias[col];
          ((float*)Cout)[(row + r) * (long)N + col] = v;
        } else {
          ((bf16*)Cout)[(row + r) * (long)N + col] = (bf16)v;
        }
      }
    }
  }
}

// ---------------------------------------------------------------------------
// Flash attention over COMPACTED keys. grid = (L/128, N*H), 4 waves.
// Loop runs ceil(cnt/64) tiles; tail tile masks j>=cnt with -1e20.
// K LDS XOR-swizzled via pre-swizzled global source (rule #21); V^T reg-staged
// swizzled. Swapped QK^T (S^T) -> thread-local softmax rows. T13 defer-max.
// Op may alias Qp: block reads its exclusive Q slice into regs before writing.
// ---------------------------------------------------------------------------
__global__ __launch_bounds__(256) void attn_fwd(const bf16* __restrict__ Qp,
                                                const bf16* __restrict__ Kp,
                                                const bf16* __restrict__ Vp,
                                                const int* __restrict__ cnts,
                                                bf16* __restrict__ Op) {
  constexpr int L = 2048, E = 2048, D = 128, KVB = 64;
  __shared__ bf16 Kt[KVB * D];    // [j][d] 16KB, swizzled slots
  __shared__ bf16 VT[D * KVB];    // [d][j] 16KB, swizzled
  __shared__ bf16 Pt[128 * 72];   // [q][j] pad-stride 18KB
  const int t = threadIdx.x, l = t & 63, w = t >> 6;
  const int l15 = l & 15, l4 = l >> 4;
  const int n = blockIdx.y >> 4, h = blockIdx.y & 15;
  const int q0 = blockIdx.x * 128;
  const int wq = w * 32;
  const float scale = 0.022097086912079608f;  // E^-0.5

  const bf16* Qb = Qp + ((long)n * L + q0) * E + h * D;
  const bf16* Kb = Kp + (long)n * L * E + h * D;
  const bf16* Vb = Vp + (long)n * L * E + h * D;
  const int cnt = cnts[n];
  const int ntk = (cnt + 63) >> 6;

  bf16x8 qf[2][4];
#pragma unroll
  for (int mi = 0; mi < 2; ++mi)
#pragma unroll
    for (int kk = 0; kk < 4; ++kk)
      qf[mi][kk] = *(const bf16x8*)(Qb + (long)(wq + mi * 16 + l15) * E + kk * 32 + l4 * 8);

  f32x4 o[2][8];
#pragma unroll
  for (int mi = 0; mi < 2; ++mi)
#pragma unroll
    for (int ni = 0; ni < 8; ++ni) o[mi][ni] = (f32x4){0.f, 0.f, 0.f, 0.f};
  float mreg[2] = {-1e20f, -1e20f};
  float lreg[2] = {0.f, 0.f};

  const int vd0 = (t >> 4) * 8;
  const int vj0 = (t & 15) * 4;

  for (int ti = 0; ti < ntk; ++ti) {
    const int kv = ti << 6;
    // ---- stage K: linear LDS dest + pre-swizzled global source
#pragma unroll
    for (int i = 0; i < 4; ++i) {
      int chunk = w * 4 + i;
      int row = chunk * 4 + l4;
      int srcslot = l15 ^ (row & 7);
      gload_lds16(Kb + (long)(kv + row) * E + srcslot * 8, Kt + chunk * 512);
    }
    // ---- stage V^T, swizzled write
    bf16x8 vr[4];
#pragma unroll
    for (int r = 0; r < 4; ++r)
      vr[r] = *(const bf16x8*)(Vb + (long)(kv + vj0 + r) * E + vd0);
#pragma unroll
    for (int i = 0; i < 8; ++i) {
      int d = vd0 + i;
      bf16x4 pk = { vr[0][i], vr[1][i], vr[2][i], vr[3][i] };
      *(bf16x4*)(VT + d * KVB + (vj0 ^ ((d & 7) << 3))) = pk;
    }
    __syncthreads();

    // ---- S^T = K Q^T
    f32x4 s[2][4];
#pragma unroll
    for (int mi = 0; mi < 2; ++mi)
#pragma unroll
      for (int ni = 0; ni < 4; ++ni) s[mi][ni] = (f32x4){0.f, 0.f, 0.f, 0.f};
#pragma unroll
    for (int kk = 0; kk < 4; ++kk) {
      bf16x8 kf[4];
#pragma unroll
      for (int ni = 0; ni < 4; ++ni) {
        int row = ni * 16 + l15;
        int slot = (kk * 4 + l4) ^ (l15 & 7);
        kf[ni] = *(const bf16x8*)(Kt + row * D + slot * 8);
      }
#pragma unroll
      for (int mi = 0; mi < 2; ++mi)
#pragma unroll
        for (int ni = 0; ni < 4; ++ni)
          s[mi][ni] = MFMA16(kf[ni], qf[mi][kk], s[mi][ni]);
    }

    // ---- scale (+ tail mask j>=cnt)
    if (kv + KVB > cnt) {
#pragma unroll
      for (int mi = 0; mi < 2; ++mi)
#pragma unroll
        for (int ni = 0; ni < 4; ++ni)
#pragma unroll
          for (int r = 0; r < 4; ++r) {
            int j = kv + ni * 16 + l4 * 4 + r;
            s[mi][ni][r] = (j < cnt) ? s[mi][ni][r] * scale : -1e20f;
          }
    } else {
#pragma unroll
      for (int mi = 0; mi < 2; ++mi)
#pragma unroll
        for (int ni = 0; ni < 4; ++ni)
#pragma unroll
          for (int r = 0; r < 4; ++r) s[mi][ni][r] *= scale;
    }

    // ---- online softmax, thread-local row; T13 defer-max
    bool need[2];
    float corr[2];
#pragma unroll
    for (int mi = 0; mi < 2; ++mi) {
      float vmax = -1e20f;
#pragma unroll
      for (int ni = 0; ni < 4; ++ni)
#pragma unroll
        for (int r = 0; r < 4; ++r) vmax = fmaxf(vmax, s[mi][ni][r]);
      vmax = fmaxf(vmax, __shfl_xor(vmax, 16));
      vmax = fmaxf(vmax, __shfl_xor(vmax, 32));
      bool nd = vmax > mreg[mi] + 8.0f;
      float mn = nd ? vmax : mreg[mi];
      corr[mi] = nd ? __expf(mreg[mi] - vmax) : 1.0f;
      need[mi] = nd;
      mreg[mi] = mn;
      float rsum = 0.f;
#pragma unroll
      for (int ni = 0; ni < 4; ++ni) {
        bf16x4 pk;
#pragma unroll
        for (int r = 0; r < 4; ++r) {
          float p = __expf(s[mi][ni][r] - mn);
          rsum += p;
          pk[r] = (bf16)p;
        }
        *(bf16x4*)(Pt + (wq + mi * 16 + l15) * 72 + ni * 16 + l4 * 4) = pk;
      }
      rsum += __shfl_xor(rsum, 16);
      rsum += __shfl_xor(rsum, 32);
      lreg[mi] = lreg[mi] * corr[mi] + rsum;
    }
    if (__any(need[0] || need[1])) {
#pragma unroll
      for (int mi = 0; mi < 2; ++mi) {
#pragma unroll
        for (int r = 0; r < 4; ++r) {
          float cr = __shfl(corr[mi], (l >> 4) * 20 + r);
#pragma unroll
          for (int ni = 0; ni < 8; ++ni) o[mi][ni][r] *= cr;
        }
      }
    }

    // ---- O += P V  (Pt rows written by this same wave: in-order DS)
#pragma unroll
    for (int kk = 0; kk < 2; ++kk) {
      bf16x8 pa[2], vb[8];
#pragma unroll
      for (int mi = 0; mi < 2; ++mi)
        pa[mi] = *(const bf16x8*)(Pt + (wq + mi * 16 + l15) * 72 + kk * 32 + l4 * 8);
#pragma unroll
      for (int ni = 0; ni < 8; ++ni) {
        int d = ni * 16 + l15;
        int col = (kk * 32 + l4 * 8) ^ ((d & 7) << 3);
        vb[ni] = *(const bf16x8*)(VT + d * KVB + col);
      }
#pragma unroll
      for (int mi = 0; mi < 2; ++mi)
#pragma unroll
        for (int ni = 0; ni < 8; ++ni)
          o[mi][ni] = MFMA16(pa[mi], vb[ni], o[mi][ni]);
    }
    __syncthreads();
  }

  // ---- epilogue
  float inv[2];
#pragma unroll
  for (int mi = 0; mi < 2; ++mi) inv[mi] = 1.f / lreg[mi];
#pragma unroll
  for (int mi = 0; mi < 2; ++mi) {
#pragma unroll
    for (int r = 0; r < 4; ++r) {
      float iv = __shfl(inv[mi], (l >> 4) * 20 + r);
      long grow = (long)n * L + q0 + wq + mi * 16 + l4 * 4 + r;
#pragma unroll
      for (int ni = 0; ni < 8; ++ni)
        Op[grow * E + h * D + ni * 16 + l15] = (bf16)(o[mi][ni][r] * iv);
    }
  }
}

// ---------------------------------------------------------------------------
extern "C" void kernel_launch(void* const* d_in, const int* in_sizes, int n_in,
                              void* d_out, int out_size, void* d_ws, size_t ws_size,
                              hipStream_t stream) {
  (void)in_sizes; (void)n_in; (void)out_size; (void)ws_size;
  const float* query = (const float*)d_in[0];
  const float* keys  = (const float*)d_in[1];
  const float* values= (const float*)d_in[2];
  const int*   mask  = (const int*)d_in[3];
  const float* Wq = (const float*)d_in[4];
  const float* Wk = (const float*)d_in[5];
  const float* Wv = (const float*)d_in[6];
  const float* Wo = (const float*)d_in[7];
  const float* bo = (const float*)d_in[8];
  float* out = (float*)d_out;

  const int N = 4, L = 2048, E = 2048;
  const int M = N * L;  // 8192
  const long EE = (long)E * E;
  const long ME = (long)M * E;

  bf16* Wqb = (bf16*)d_ws;
  bf16* Wkb = Wqb + EE;
  bf16* Wvb = Wkb + EE;
  bf16* Wob = Wvb + EE;
  bf16* qp  = Wob + EE;     // attn output aliases qp (exclusive per-block slices)
  bf16* kp  = qp + ME;
  bf16* vp  = kp + ME;
  int*  idx = (int*)(vp + ME);
  int*  cnts = idx + N * 2048;

  // 1) weights -> bf16; mask compaction
  int cbw = (int)(EE / 4 / 256);
  cvt_bf16<<<cbw, 256, 0, stream>>>(Wq, Wqb, EE);
  cvt_bf16<<<cbw, 256, 0, stream>>>(Wk, Wkb, EE);
  cvt_bf16<<<cbw, 256, 0, stream>>>(Wv, Wvb, EE);
  cvt_bf16<<<cbw, 256, 0, stream>>>(Wo, Wob, EE);
  mask_compact<<<4, 256, 0, stream>>>(mask, idx, cnts);

  // 2) projections
  dim3 gg(E / 128, M / 128);  // (16, 64)
  gemm_bt<1, 0, 0><<<gg, 256, 0, stream>>>(query,  Wqb, qp, nullptr, nullptr, nullptr, M, E, E);
  gemm_bt<2, 0, 0><<<gg, 256, 0, stream>>>(keys,   Wkb, kp, nullptr, idx, cnts, M, E, E);
  gemm_bt<2, 0, 0><<<gg, 256, 0, stream>>>(values, Wvb, vp, nullptr, idx, cnts, M, E, E);

  // 3) attention over compacted keys (output aliases qp)
  attn_fwd<<<dim3(L / 128, N * 16), 256, 0, stream>>>(qp, kp, vp, cnts, qp);

  // 4) output projection + bias
  gemm_bt<0, 1, 1><<<gg, 256, 0, stream>>>(qp, Wob, out, bo, nullptr, nullptr, M, E, E);
}

// Round 4
// 496.193 us; speedup vs baseline: 1.9025x; 1.3474x over previous
//
#include <hip/hip_runtime.h>
#include <stdint.h>

// ---------------------------------------------------------------------------
// MultiHeadAttention: out = softmax(mask((X Wq^T)(X Wk^T)^T * E^-0.5)) (X Wv^T) Wo^T + bo
// N=4, L=2048, E=2048, H=16, D=128.  bf16 MFMA GEMMs, f32 softmax.
// R3 -> R4: projection GEMMs rebuilt as 256x256 counted-vmcnt pipeline
// (T3+T4: raw s_barrier + vmcnt(8), double-buffered 128KB LDS, T2 swizzle,
// T5 setprio). A-operands pre-converted to bf16 (query: cvt; keys/values:
// fused gather+cvt over compacted indices). Attention unchanged from R3.
// Workspace (136MB + 64KB):
//   [0,64KB)        idx (int[4][2048]), cnts (int[8])
//   [64KB, +8MB)    wslot (bf16 weight, reused for Wq/Wk/Wv/Wo sequentially)
//   [+32MB)         xs  (bf16 staged/gathered activations [8192][2048])
//   [+32MB)         qp  (Q proj; attn output aliases this)
//   [+32MB)         kp  (compacted K proj)
//   [+32MB)         vp  (compacted V proj)
// ---------------------------------------------------------------------------

typedef __bf16 bf16;
typedef __bf16 bf16x4 __attribute__((ext_vector_type(4)));
typedef __bf16 bf16x8 __attribute__((ext_vector_type(8)));
typedef float  f32x4  __attribute__((ext_vector_type(4)));

#define MFMA16(a, b, c) __builtin_amdgcn_mfma_f32_16x16x32_bf16(a, b, c, 0, 0, 0)

__device__ __forceinline__ void gload_lds16(const void* g, void* s) {
  __builtin_amdgcn_global_load_lds(
      (const __attribute__((address_space(1))) void*)g,
      (__attribute__((address_space(3))) void*)s, 16, 0, 0);
}

// ---------------------------------------------------------------------------
__global__ __launch_bounds__(256) void cvt_bf16(const float* __restrict__ src,
                                                bf16* __restrict__ dst, long n) {
  long i = ((long)blockIdx.x * 256 + threadIdx.x) * 4;
  if (i < n) {
    f32x4 f = *(const f32x4*)(src + i);
    bf16x4 h = { (bf16)f.x, (bf16)f.y, (bf16)f.z, (bf16)f.w };
    *(bf16x4*)(dst + i) = h;
  }
}

// Gather rows through compacted idx while converting f32->bf16.
// Out row g (0..8191): n=g>>11, p=g&2047; src row = n*2048 + idx[n*2048+p].
__global__ __launch_bounds__(256) void gather_cvt(const float* __restrict__ src,
                                                  bf16* __restrict__ dst,
                                                  const int* __restrict__ idx) {
  long i = (long)blockIdx.x * 256 + threadIdx.x;  // unit of 8 elements
  int row = (int)(i >> 8);                        // 256 units per 2048-col row
  int u = (int)(i & 255);
  int n = row >> 11, p = row & 2047;
  long srow = ((long)n << 11) + idx[(n << 11) + p];
  const float* s = src + srow * 2048 + u * 8;
  f32x4 a = *(const f32x4*)s;
  f32x4 b = *(const f32x4*)(s + 4);
  bf16x8 h = { (bf16)a.x, (bf16)a.y, (bf16)a.z, (bf16)a.w,
               (bf16)b.x, (bf16)b.y, (bf16)b.z, (bf16)b.w };
  *(bf16x8*)(dst + (long)row * 2048 + u * 8) = h;
}

// ---------------------------------------------------------------------------
// Per-n compaction of mask==1 indices. grid = 4 x 256.
// ---------------------------------------------------------------------------
__global__ __launch_bounds__(256) void mask_compact(const int* __restrict__ mask,
                                                    int* __restrict__ idx,
                                                    int* __restrict__ cnts) {
  const int n = blockIdx.x;
  const int t = threadIdx.x, l = t & 63, w = t >> 6;
  const int* m = mask + n * 2048;
  __shared__ int wtot[4];
  int f[8], tt = 0;
  const int base = t * 8;
#pragma unroll
  for (int i = 0; i < 8; ++i) { f[i] = (m[base + i] != 0); tt += f[i]; }
  int sc = tt;
#pragma unroll
  for (int d = 1; d < 64; d <<= 1) {
    int v = __shfl_up(sc, d);
    if (l >= d) sc += v;
  }
  if (l == 63) wtot[w] = sc;
  __syncthreads();
  int woff = 0;
#pragma unroll
  for (int i = 0; i < 4; ++i) if (i < w) woff += wtot[i];
  int off = woff + sc - tt;
#pragma unroll
  for (int i = 0; i < 8; ++i)
    if (f[i]) { idx[n * 2048 + off] = base + i; ++off; }
  int total = wtot[0] + wtot[1] + wtot[2] + wtot[3];
  for (int p = total + t; p < 2048; p += 256) idx[n * 2048 + p] = 2047;
  if (t == 0) { cnts[n] = total; cnts[4 + n] = (total + 127) & ~127; }
}

// ---------------------------------------------------------------------------
// 256x256 GEMM, C[M,2048] = A[M,2048] @ B[2048,2048]^T, M=8192, bf16 MFMA.
// 512 threads = 8 waves (2Mx4N), each wave 128x64 out. BK=64, 32 K-tiles.
// Double-buffered 128KB LDS; counted vmcnt(8) pipeline with raw s_barrier
// (no __syncthreads -> no vmcnt(0) drain). T2 swizzle slot16 ^= row&7 on
// gload source + ds_read (rule #21). T5 setprio around MFMA clusters.
// AEXIT: skip M-blocks past cnts[4+n] (compacted K/V projections).
// ---------------------------------------------------------------------------
template <int AEXIT, int OUT_F32, int ADD_BIAS>
__global__ __launch_bounds__(512, 2) void gemm256(const bf16* __restrict__ A,
                                                  const bf16* __restrict__ B,
                                                  void* __restrict__ Cout,
                                                  const float* __restrict__ bias,
                                                  const int* __restrict__ cnts) {
  constexpr int K = 2048, LDC = 2048, NT = 32;      // K-tiles of 64
  constexpr int TILE = 256 * 64;                    // elems per operand tile
  __shared__ bf16 S[2 * 2 * TILE];                  // [parity][A|B] 128KB
  const int t = threadIdx.x;
  const int l = t & 63, w = t >> 6;
  const int wr = w >> 2, wc = w & 3;
  const int l15 = l & 15, l4 = l >> 4;

  // XCD-chunked M-block remap: XCD c (= bx&7) owns Mb in [4c, 4c+4)
  const int Mb = ((blockIdx.x & 7) << 2) + (blockIdx.x >> 3);
  const long tm = (long)Mb * 256;
  const long tn = (long)blockIdx.y * 256;

  if constexpr (AEXIT) {
    int n = (int)(tm >> 11);
    if ((int)(tm & 2047) >= cnts[4 + n]) return;
  }

  const bf16* Ab = A + tm * K;
  const bf16* Bb = B + tn * K;

  // ---- stage one 64-wide K-tile (A+B) into parity p: 8 gloads/thread
  auto stage = [&](int T, int p) {
    bf16* sA = S + p * 2 * TILE;
    bf16* sB = sA + TILE;
    const bf16* Ak = Ab + T * 64;
    const bf16* Bk = Bb + T * 64;
#pragma unroll
    for (int i = 0; i < 4; ++i) {
      int u = i * 512 + t;
      int row = u >> 3, slot = u & 7;
      int ss = slot ^ (row & 7);                    // pre-swizzled source
      gload_lds16(Ak + (long)row * K + ss * 8, sA + u * 8);
    }
#pragma unroll
    for (int i = 0; i < 4; ++i) {
      int u = i * 512 + t;
      int row = u >> 3, slot = u & 7;
      int ss = slot ^ (row & 7);
      gload_lds16(Bk + (long)row * K + ss * 8, sB + u * 8);
    }
  };

  f32x4 acc[8][4];
#pragma unroll
  for (int i = 0; i < 8; ++i)
#pragma unroll
    for (int j = 0; j < 4; ++j) acc[i][j] = (f32x4){0.f, 0.f, 0.f, 0.f};

  stage(0, 0);  // prologue

  for (int T = 0; T < NT; ++T) {
    const int p = T & 1;
    const bf16* sA = S + p * 2 * TILE;
    const bf16* sB = sA + TILE;

    asm volatile("" ::: "memory");
    __builtin_amdgcn_s_barrier();        // barrier#1: buf p^1 free everywhere
    asm volatile("" ::: "memory");
    if (T + 1 < NT) {
      stage(T + 1, p ^ 1);
      asm volatile("s_waitcnt vmcnt(8)" ::: "memory");  // T landed, T+1 in flight
    } else {
      asm volatile("s_waitcnt vmcnt(0)" ::: "memory");
    }
    __builtin_amdgcn_s_barrier();        // barrier#2: tile T visible to all
    asm volatile("" ::: "memory");

#pragma unroll
    for (int kk = 0; kk < 2; ++kk) {
      bf16x8 af[8], bf[4];
#pragma unroll
      for (int mi = 0; mi < 8; ++mi) {
        int row = wr * 128 + mi * 16 + l15;
        int slot = (kk * 4 + l4) ^ (row & 7);
        af[mi] = *(const bf16x8*)(sA + row * 64 + slot * 8);
      }
#pragma unroll
      for (int ni = 0; ni < 4; ++ni) {
        int row = wc * 64 + ni * 16 + l15;
        int slot = (kk * 4 + l4) ^ (row & 7);
        bf[ni] = *(const bf16x8*)(sB + row * 64 + slot * 8);
      }
      __builtin_amdgcn_s_setprio(1);
#pragma unroll
      for (int mi = 0; mi < 8; ++mi)
#pragma unroll
        for (int ni = 0; ni < 4; ++ni)
          acc[mi][ni] = MFMA16(af[mi], bf[ni], acc[mi][ni]);
      __builtin_amdgcn_s_setprio(0);
    }
  }

  // ---- epilogue: row = l4*4+r side (M), col = l15 side (N)
#pragma unroll
  for (int mi = 0; mi < 8; ++mi) {
#pragma unroll
    for (int ni = 0; ni < 4; ++ni) {
      long col = tn + wc * 64 + ni * 16 + l15;
      long row = tm + wr * 128 + mi * 16 + l4 * 4;
#pragma unroll
      for (int r = 0; r < 4; ++r) {
        float v = acc[mi][ni][r];
        if constexpr (OUT_F32) {
          if constexpr (ADD_BIAS) v += bias[col];
          ((float*)Cout)[(row + r) * (long)LDC + col] = v;
        } else {
          ((bf16*)Cout)[(row + r) * (long)LDC + col] = (bf16)v;
        }
      }
    }
  }
}

// ---------------------------------------------------------------------------
// Flash attention over COMPACTED keys (unchanged from R3).
// ---------------------------------------------------------------------------
__global__ __launch_bounds__(256) void attn_fwd(const bf16* __restrict__ Qp,
                                                const bf16* __restrict__ Kp,
                                                const bf16* __restrict__ Vp,
                                                const int* __restrict__ cnts,
                                                bf16* __restrict__ Op) {
  constexpr int L = 2048, E = 2048, D = 128, KVB = 64;
  __shared__ bf16 Kt[KVB * D];
  __shared__ bf16 VT[D * KVB];
  __shared__ bf16 Pt[128 * 72];
  const int t = threadIdx.x, l = t & 63, w = t >> 6;
  const int l15 = l & 15, l4 = l >> 4;
  const int n = blockIdx.y >> 4, h = blockIdx.y & 15;
  const int q0 = blockIdx.x * 128;
  const int wq = w * 32;
  const float scale = 0.022097086912079608f;  // E^-0.5

  const bf16* Qb = Qp + ((long)n * L + q0) * E + h * D;
  const bf16* Kb = Kp + (long)n * L * E + h * D;
  const bf16* Vb = Vp + (long)n * L * E + h * D;
  const int cnt = cnts[n];
  const int ntk = (cnt + 63) >> 6;

  bf16x8 qf[2][4];
#pragma unroll
  for (int mi = 0; mi < 2; ++mi)
#pragma unroll
    for (int kk = 0; kk < 4; ++kk)
      qf[mi][kk] = *(const bf16x8*)(Qb + (long)(wq + mi * 16 + l15) * E + kk * 32 + l4 * 8);

  f32x4 o[2][8];
#pragma unroll
  for (int mi = 0; mi < 2; ++mi)
#pragma unroll
    for (int ni = 0; ni < 8; ++ni) o[mi][ni] = (f32x4){0.f, 0.f, 0.f, 0.f};
  float mreg[2] = {-1e20f, -1e20f};
  float lreg[2] = {0.f, 0.f};

  const int vd0 = (t >> 4) * 8;
  const int vj0 = (t & 15) * 4;

  for (int ti = 0; ti < ntk; ++ti) {
    const int kv = ti << 6;
#pragma unroll
    for (int i = 0; i < 4; ++i) {
      int chunk = w * 4 + i;
      int row = chunk * 4 + l4;
      int srcslot = l15 ^ (row & 7);
      gload_lds16(Kb + (long)(kv + row) * E + srcslot * 8, Kt + chunk * 512);
    }
    bf16x8 vr[4];
#pragma unroll
    for (int r = 0; r < 4; ++r)
      vr[r] = *(const bf16x8*)(Vb + (long)(kv + vj0 + r) * E + vd0);
#pragma unroll
    for (int i = 0; i < 8; ++i) {
      int d = vd0 + i;
      bf16x4 pk = { vr[0][i], vr[1][i], vr[2][i], vr[3][i] };
      *(bf16x4*)(VT + d * KVB + (vj0 ^ ((d & 7) << 3))) = pk;
    }
    __syncthreads();

    f32x4 s[2][4];
#pragma unroll
    for (int mi = 0; mi < 2; ++mi)
#pragma unroll
      for (int ni = 0; ni < 4; ++ni) s[mi][ni] = (f32x4){0.f, 0.f, 0.f, 0.f};
#pragma unroll
    for (int kk = 0; kk < 4; ++kk) {
      bf16x8 kf[4];
#pragma unroll
      for (int ni = 0; ni < 4; ++ni) {
        int row = ni * 16 + l15;
        int slot = (kk * 4 + l4) ^ (l15 & 7);
        kf[ni] = *(const bf16x8*)(Kt + row * D + slot * 8);
      }
#pragma unroll
      for (int mi = 0; mi < 2; ++mi)
#pragma unroll
        for (int ni = 0; ni < 4; ++ni)
          s[mi][ni] = MFMA16(kf[ni], qf[mi][kk], s[mi][ni]);
    }

    if (kv + KVB > cnt) {
#pragma unroll
      for (int mi = 0; mi < 2; ++mi)
#pragma unroll
        for (int ni = 0; ni < 4; ++ni)
#pragma unroll
          for (int r = 0; r < 4; ++r) {
            int j = kv + ni * 16 + l4 * 4 + r;
            s[mi][ni][r] = (j < cnt) ? s[mi][ni][r] * scale : -1e20f;
          }
    } else {
#pragma unroll
      for (int mi = 0; mi < 2; ++mi)
#pragma unroll
        for (int ni = 0; ni < 4; ++ni)
#pragma unroll
          for (int r = 0; r < 4; ++r) s[mi][ni][r] *= scale;
    }

    bool need[2];
    float corr[2];
#pragma unroll
    for (int mi = 0; mi < 2; ++mi) {
      float vmax = -1e20f;
#pragma unroll
      for (int ni = 0; ni < 4; ++ni)
#pragma unroll
        for (int r = 0; r < 4; ++r) vmax = fmaxf(vmax, s[mi][ni][r]);
      vmax = fmaxf(vmax, __shfl_xor(vmax, 16));
      vmax = fmaxf(vmax, __shfl_xor(vmax, 32));
      bool nd = vmax > mreg[mi] + 8.0f;
      float mn = nd ? vmax : mreg[mi];
      corr[mi] = nd ? __expf(mreg[mi] - vmax) : 1.0f;
      need[mi] = nd;
      mreg[mi] = mn;
      float rsum = 0.f;
#pragma unroll
      for (int ni = 0; ni < 4; ++ni) {
        bf16x4 pk;
#pragma unroll
        for (int r = 0; r < 4; ++r) {
          float p = __expf(s[mi][ni][r] - mn);
          rsum += p;
          pk[r] = (bf16)p;
        }
        *(bf16x4*)(Pt + (wq + mi * 16 + l15) * 72 + ni * 16 + l4 * 4) = pk;
      }
      rsum += __shfl_xor(rsum, 16);
      rsum += __shfl_xor(rsum, 32);
      lreg[mi] = lreg[mi] * corr[mi] + rsum;
    }
    if (__any(need[0] || need[1])) {
#pragma unroll
      for (int mi = 0; mi < 2; ++mi) {
#pragma unroll
        for (int r = 0; r < 4; ++r) {
          float cr = __shfl(corr[mi], (l >> 4) * 20 + r);
#pragma unroll
          for (int ni = 0; ni < 8; ++ni) o[mi][ni][r] *= cr;
        }
      }
    }

#pragma unroll
    for (int kk = 0; kk < 2; ++kk) {
      bf16x8 pa[2], vb[8];
#pragma unroll
      for (int mi = 0; mi < 2; ++mi)
        pa[mi] = *(const bf16x8*)(Pt + (wq + mi * 16 + l15) * 72 + kk * 32 + l4 * 8);
#pragma unroll
      for (int ni = 0; ni < 8; ++ni) {
        int d = ni * 16 + l15;
        int col = (kk * 32 + l4 * 8) ^ ((d & 7) << 3);
        vb[ni] = *(const bf16x8*)(VT + d * KVB + col);
      }
#pragma unroll
      for (int mi = 0; mi < 2; ++mi)
#pragma unroll
        for (int ni = 0; ni < 8; ++ni)
          o[mi][ni] = MFMA16(pa[mi], vb[ni], o[mi][ni]);
    }
    __syncthreads();
  }

  float inv[2];
#pragma unroll
  for (int mi = 0; mi < 2; ++mi) inv[mi] = 1.f / lreg[mi];
#pragma unroll
  for (int mi = 0; mi < 2; ++mi) {
#pragma unroll
    for (int r = 0; r < 4; ++r) {
      float iv = __shfl(inv[mi], (l >> 4) * 20 + r);
      long grow = (long)n * L + q0 + wq + mi * 16 + l4 * 4 + r;
#pragma unroll
      for (int ni = 0; ni < 8; ++ni)
        Op[grow * E + h * D + ni * 16 + l15] = (bf16)(o[mi][ni][r] * iv);
    }
  }
}

// ---------------------------------------------------------------------------
extern "C" void kernel_launch(void* const* d_in, const int* in_sizes, int n_in,
                              void* d_out, int out_size, void* d_ws, size_t ws_size,
                              hipStream_t stream) {
  (void)in_sizes; (void)n_in; (void)out_size; (void)ws_size;
  const float* query = (const float*)d_in[0];
  const float* keys  = (const float*)d_in[1];
  const float* values= (const float*)d_in[2];
  const int*   mask  = (const int*)d_in[3];
  const float* Wq = (const float*)d_in[4];
  const float* Wk = (const float*)d_in[5];
  const float* Wv = (const float*)d_in[6];
  const float* Wo = (const float*)d_in[7];
  const float* bo = (const float*)d_in[8];
  float* out = (float*)d_out;

  const int N = 4, L = 2048, E = 2048;
  const int M = N * L;  // 8192
  const long EE = (long)E * E;
  const long ME = (long)M * E;

  int*  idx  = (int*)d_ws;
  int*  cnts = idx + N * 2048;
  bf16* wslot= (bf16*)((char*)d_ws + 65536);
  bf16* xs   = wslot + EE;
  bf16* qp   = xs + ME;
  bf16* kp   = qp + ME;
  bf16* vp   = kp + ME;

  const int cbw = (int)(EE / 4 / 256);   // weight cvt blocks
  const int cba = (int)(ME / 4 / 256);   // activation cvt blocks
  const int gbl = (int)(ME / 8 / 256);   // gather blocks (8 elems/thread)
  dim3 gg(32, 8);                        // 256 blocks = 1/CU

  mask_compact<<<4, 256, 0, stream>>>(mask, idx, cnts);

  // Q projection
  cvt_bf16<<<cbw, 256, 0, stream>>>(Wq, wslot, EE);
  cvt_bf16<<<cba, 256, 0, stream>>>(query, xs, ME);
  gemm256<0, 0, 0><<<gg, 512, 0, stream>>>(xs, wslot, qp, nullptr, cnts);

  // K projection (gathered/compacted)
  cvt_bf16<<<cbw, 256, 0, stream>>>(Wk, wslot, EE);
  gather_cvt<<<gbl, 256, 0, stream>>>(keys, xs, idx);
  gemm256<1, 0, 0><<<gg, 512, 0, stream>>>(xs, wslot, kp, nullptr, cnts);

  // V projection (gathered/compacted)
  cvt_bf16<<<cbw, 256, 0, stream>>>(Wv, wslot, EE);
  gather_cvt<<<gbl, 256, 0, stream>>>(values, xs, idx);
  gemm256<1, 0, 0><<<gg, 512, 0, stream>>>(xs, wslot, vp, nullptr, cnts);

  // attention over compacted keys (output aliases qp)
  attn_fwd<<<dim3(L / 128, N * 16), 256, 0, stream>>>(qp, kp, vp, cnts, qp);

  // output projection + bias
  cvt_bf16<<<cbw, 256, 0, stream>>>(Wo, wslot, EE);
  gemm256<0, 1, 1><<<gg, 512, 0, stream>>>(qp, wslot, out, bo, cnts);
}

// Round 5
// 478.744 us; speedup vs baseline: 1.9718x; 1.0364x over previous
//
#include <hip/hip_runtime.h>
#include <stdint.h>

// ---------------------------------------------------------------------------
// MultiHeadAttention: out = softmax(mask((X Wq^T)(X Wk^T)^T * E^-0.5)) (X Wv^T) Wo^T + bo
// N=4, L=2048, E=2048, H=16, D=128.  bf16 MFMA GEMMs, f32 softmax.
// R4 -> R5: attention rebuilt: 8 waves x 16 q-rows (512 thr, VGPR diet ->
// 4 waves/SIMD), double-buffered K/V staging (issue-early/write-late, T14),
// in-register P redistribution via packed-bf16 shfl (no Pt LDS, no conflicts),
// XCD-swizzled grid (K/V slice L2-locality). GEMM/cvt path unchanged from R4.
// Workspace (136MB + 64KB):
//   [0,64KB)        idx (int[4][2048]), cnts (int[8])
//   [64KB, +8MB)    wslot (bf16 weight, reused for Wq/Wk/Wv/Wo sequentially)
//   [+32MB)         xs  (bf16 staged/gathered activations [8192][2048])
//   [+32MB)         qp  (Q proj; attn output aliases this)
//   [+32MB)         kp  (compacted K proj)
//   [+32MB)         vp  (compacted V proj)
// ---------------------------------------------------------------------------

typedef __bf16 bf16;
typedef __bf16 bf16x2 __attribute__((ext_vector_type(2)));
typedef __bf16 bf16x4 __attribute__((ext_vector_type(4)));
typedef __bf16 bf16x8 __attribute__((ext_vector_type(8)));
typedef float  f32x4  __attribute__((ext_vector_type(4)));
typedef uint32_t u32x4 __attribute__((ext_vector_type(4)));

#define MFMA16(a, b, c) __builtin_amdgcn_mfma_f32_16x16x32_bf16(a, b, c, 0, 0, 0)

__device__ __forceinline__ void gload_lds16(const void* g, void* s) {
  __builtin_amdgcn_global_load_lds(
      (const __attribute__((address_space(1))) void*)g,
      (__attribute__((address_space(3))) void*)s, 16, 0, 0);
}

__device__ __forceinline__ uint32_t pkbf(float a, float b) {
  return __builtin_bit_cast(uint32_t, (bf16x2){(bf16)a, (bf16)b});
}

// ---------------------------------------------------------------------------
__global__ __launch_bounds__(256) void cvt_bf16(const float* __restrict__ src,
                                                bf16* __restrict__ dst, long n) {
  long i = ((long)blockIdx.x * 256 + threadIdx.x) * 4;
  if (i < n) {
    f32x4 f = *(const f32x4*)(src + i);
    bf16x4 h = { (bf16)f.x, (bf16)f.y, (bf16)f.z, (bf16)f.w };
    *(bf16x4*)(dst + i) = h;
  }
}

// Gather rows through compacted idx while converting f32->bf16.
__global__ __launch_bounds__(256) void gather_cvt(const float* __restrict__ src,
                                                  bf16* __restrict__ dst,
                                                  const int* __restrict__ idx) {
  long i = (long)blockIdx.x * 256 + threadIdx.x;  // unit of 8 elements
  int row = (int)(i >> 8);
  int u = (int)(i & 255);
  int n = row >> 11, p = row & 2047;
  long srow = ((long)n << 11) + idx[(n << 11) + p];
  const float* s = src + srow * 2048 + u * 8;
  f32x4 a = *(const f32x4*)s;
  f32x4 b = *(const f32x4*)(s + 4);
  bf16x8 h = { (bf16)a.x, (bf16)a.y, (bf16)a.z, (bf16)a.w,
               (bf16)b.x, (bf16)b.y, (bf16)b.z, (bf16)b.w };
  *(bf16x8*)(dst + (long)row * 2048 + u * 8) = h;
}

// ---------------------------------------------------------------------------
// Per-n compaction of mask==1 indices. grid = 4 x 256.
// ---------------------------------------------------------------------------
__global__ __launch_bounds__(256) void mask_compact(const int* __restrict__ mask,
                                                    int* __restrict__ idx,
                                                    int* __restrict__ cnts) {
  const int n = blockIdx.x;
  const int t = threadIdx.x, l = t & 63, w = t >> 6;
  const int* m = mask + n * 2048;
  __shared__ int wtot[4];
  int f[8], tt = 0;
  const int base = t * 8;
#pragma unroll
  for (int i = 0; i < 8; ++i) { f[i] = (m[base + i] != 0); tt += f[i]; }
  int sc = tt;
#pragma unroll
  for (int d = 1; d < 64; d <<= 1) {
    int v = __shfl_up(sc, d);
    if (l >= d) sc += v;
  }
  if (l == 63) wtot[w] = sc;
  __syncthreads();
  int woff = 0;
#pragma unroll
  for (int i = 0; i < 4; ++i) if (i < w) woff += wtot[i];
  int off = woff + sc - tt;
#pragma unroll
  for (int i = 0; i < 8; ++i)
    if (f[i]) { idx[n * 2048 + off] = base + i; ++off; }
  int total = wtot[0] + wtot[1] + wtot[2] + wtot[3];
  for (int p = total + t; p < 2048; p += 256) idx[n * 2048 + p] = 2047;
  if (t == 0) { cnts[n] = total; cnts[4 + n] = (total + 127) & ~127; }
}

// ---------------------------------------------------------------------------
// 256x256 GEMM (unchanged from R4): counted-vmcnt double-buffered pipeline.
// ---------------------------------------------------------------------------
template <int AEXIT, int OUT_F32, int ADD_BIAS>
__global__ __launch_bounds__(512, 2) void gemm256(const bf16* __restrict__ A,
                                                  const bf16* __restrict__ B,
                                                  void* __restrict__ Cout,
                                                  const float* __restrict__ bias,
                                                  const int* __restrict__ cnts) {
  constexpr int K = 2048, LDC = 2048, NT = 32;
  constexpr int TILE = 256 * 64;
  __shared__ bf16 S[2 * 2 * TILE];
  const int t = threadIdx.x;
  const int l = t & 63, w = t >> 6;
  const int wr = w >> 2, wc = w & 3;
  const int l15 = l & 15, l4 = l >> 4;

  const int Mb = ((blockIdx.x & 7) << 2) + (blockIdx.x >> 3);
  const long tm = (long)Mb * 256;
  const long tn = (long)blockIdx.y * 256;

  if constexpr (AEXIT) {
    int n = (int)(tm >> 11);
    if ((int)(tm & 2047) >= cnts[4 + n]) return;
  }

  const bf16* Ab = A + tm * K;
  const bf16* Bb = B + tn * K;

  auto stage = [&](int T, int p) {
    bf16* sA = S + p * 2 * TILE;
    bf16* sB = sA + TILE;
    const bf16* Ak = Ab + T * 64;
    const bf16* Bk = Bb + T * 64;
#pragma unroll
    for (int i = 0; i < 4; ++i) {
      int u = i * 512 + t;
      int row = u >> 3, slot = u & 7;
      int ss = slot ^ (row & 7);
      gload_lds16(Ak + (long)row * K + ss * 8, sA + u * 8);
    }
#pragma unroll
    for (int i = 0; i < 4; ++i) {
      int u = i * 512 + t;
      int row = u >> 3, slot = u & 7;
      int ss = slot ^ (row & 7);
      gload_lds16(Bk + (long)row * K + ss * 8, sB + u * 8);
    }
  };

  f32x4 acc[8][4];
#pragma unroll
  for (int i = 0; i < 8; ++i)
#pragma unroll
    for (int j = 0; j < 4; ++j) acc[i][j] = (f32x4){0.f, 0.f, 0.f, 0.f};

  stage(0, 0);

  for (int T = 0; T < NT; ++T) {
    const int p = T & 1;
    const bf16* sA = S + p * 2 * TILE;
    const bf16* sB = sA + TILE;

    asm volatile("" ::: "memory");
    __builtin_amdgcn_s_barrier();
    asm volatile("" ::: "memory");
    if (T + 1 < NT) {
      stage(T + 1, p ^ 1);
      asm volatile("s_waitcnt vmcnt(8)" ::: "memory");
    } else {
      asm volatile("s_waitcnt vmcnt(0)" ::: "memory");
    }
    __builtin_amdgcn_s_barrier();
    asm volatile("" ::: "memory");

#pragma unroll
    for (int kk = 0; kk < 2; ++kk) {
      bf16x8 af[8], bf[4];
#pragma unroll
      for (int mi = 0; mi < 8; ++mi) {
        int row = wr * 128 + mi * 16 + l15;
        int slot = (kk * 4 + l4) ^ (row & 7);
        af[mi] = *(const bf16x8*)(sA + row * 64 + slot * 8);
      }
#pragma unroll
      for (int ni = 0; ni < 4; ++ni) {
        int row = wc * 64 + ni * 16 + l15;
        int slot = (kk * 4 + l4) ^ (row & 7);
        bf[ni] = *(const bf16x8*)(sB + row * 64 + slot * 8);
      }
      __builtin_amdgcn_s_setprio(1);
#pragma unroll
      for (int mi = 0; mi < 8; ++mi)
#pragma unroll
        for (int ni = 0; ni < 4; ++ni)
          acc[mi][ni] = MFMA16(af[mi], bf[ni], acc[mi][ni]);
      __builtin_amdgcn_s_setprio(0);
    }
  }

#pragma unroll
  for (int mi = 0; mi < 8; ++mi) {
#pragma unroll
    for (int ni = 0; ni < 4; ++ni) {
      long col = tn + wc * 64 + ni * 16 + l15;
      long row = tm + wr * 128 + mi * 16 + l4 * 4;
#pragma unroll
      for (int r = 0; r < 4; ++r) {
        float v = acc[mi][ni][r];
        if constexpr (OUT_F32) {
          if constexpr (ADD_BIAS) v += bias[col];
          ((float*)Cout)[(row + r) * (long)LDC + col] = v;
        } else {
          ((bf16*)Cout)[(row + r) * (long)LDC + col] = (bf16)v;
        }
      }
    }
  }
}

// ---------------------------------------------------------------------------
// Flash attention over COMPACTED keys. 1D grid 1024 blocks x 512 threads
// (8 waves x 16 q-rows). XCD-swizzled block decode: the 16 q0-blocks sharing
// one (n,h) K/V slice land on the same XCD (L2-resident slice).
// Per KV-tile (64 keys): issue K[t+1] gload_lds + V[t+1] reg-loads FIRST,
// compute tile t, then transpose-write VT[t+1] and sync (2-phase pipeline).
// Swapped QK^T -> thread-local softmax row (q = wq+l15, 16 j's). P rebuilt
// as PV A-fragment in-register: pack bf16 pairs, 16 shfl + 8 sel per tile
// (exchange confined to the 4-lane column group). T13 defer-max.
// Op aliases Qp (block reads its exclusive Q slice into regs first).
// ---------------------------------------------------------------------------
__global__ __launch_bounds__(512, 4) void attn_fwd(const bf16* __restrict__ Qp,
                                                   const bf16* __restrict__ Kp,
                                                   const bf16* __restrict__ Vp,
                                                   const int* __restrict__ cnts,
                                                   bf16* __restrict__ Op) {
  constexpr int L = 2048, E = 2048, KVB = 64;
  __shared__ bf16 Kt[2][KVB * 128];   // [j][16 slots of 8], swizzled  16KB x2
  __shared__ bf16 VT[2][128 * KVB];   // [d][j], swizzled              16KB x2
  const int t = threadIdx.x, l = t & 63, w = t >> 6;
  const int l15 = l & 15, l4 = l >> 4;

  // XCD-swizzled decode: slot = (b&7)*128 + b>>3; q0 = (slot&15)*128; y = slot>>4
  const int b = blockIdx.x;
  const int slot = ((b & 7) << 7) + (b >> 3);
  const int q0 = (slot & 15) << 7;
  const int y = slot >> 4;
  const int n = y >> 4, h = y & 15;
  const int wq = w * 16;
  const float scale = 0.022097086912079608f;  // E^-0.5

  const bf16* Qb = Qp + ((long)n * L + q0) * E + h * 128;
  const bf16* Kb = Kp + (long)n * L * E + h * 128;
  const bf16* Vb = Vp + (long)n * L * E + h * 128;
  const int cnt = cnts[n];
  const int ntk = (cnt + 63) >> 6;

  // Q fragments: rows wq+l15 (16 per wave), k-slices l4*8
  bf16x8 qf[4];
#pragma unroll
  for (int kk = 0; kk < 4; ++kk)
    qf[kk] = *(const bf16x8*)(Qb + (long)(wq + l15) * E + kk * 32 + l4 * 8);

  f32x4 o[8];
#pragma unroll
  for (int ni = 0; ni < 8; ++ni) o[ni] = (f32x4){0.f, 0.f, 0.f, 0.f};
  float mreg = -1e20f, lreg = 0.f;

  const int vd0 = (t & 31) * 4;   // 4 d's this thread transposes
  const int vj0 = (t >> 5) * 4;   // 4 j's

  auto stageK = [&](int kv, int pp) {
#pragma unroll
    for (int i = 0; i < 2; ++i) {
      int u = i * 512 + t;
      int row = u >> 4, sl = u & 15;
      gload_lds16(Kb + (long)(kv + row) * E + ((sl ^ (row & 7)) * 8),
                  &Kt[pp][u * 8]);
    }
  };
  auto loadV = [&](int kv, bf16x4* vr) {
#pragma unroll
    for (int r = 0; r < 4; ++r)
      vr[r] = *(const bf16x4*)(Vb + (long)(kv + vj0 + r) * E + vd0);
  };
  auto writeV = [&](const bf16x4* vr, int pp) {
#pragma unroll
    for (int i = 0; i < 4; ++i) {
      int d = vd0 + i;
      bf16x4 pk = { vr[0][i], vr[1][i], vr[2][i], vr[3][i] };
      *(bf16x4*)(&VT[pp][d * KVB + (vj0 ^ ((d & 7) << 3))]) = pk;
    }
  };

  // prologue: tile 0
  bf16x4 vr[4];
  stageK(0, 0);
  loadV(0, vr);
  writeV(vr, 0);
  __syncthreads();

  for (int ti = 0; ti < ntk; ++ti) {
    const int p = ti & 1;
    const int kv = ti << 6;
    const bool pre = (ti + 1) < ntk;
    if (pre) {                      // issue next tile's staging EARLY
      stageK(kv + KVB, p ^ 1);
      loadV(kv + KVB, vr);
    }

    // ---- S^T = K Q^T  (rows j, cols q)
    f32x4 s[4];
#pragma unroll
    for (int ni = 0; ni < 4; ++ni) s[ni] = (f32x4){0.f, 0.f, 0.f, 0.f};
#pragma unroll
    for (int kk = 0; kk < 4; ++kk) {
      bf16x8 kf[4];
#pragma unroll
      for (int ni = 0; ni < 4; ++ni) {
        int row = ni * 16 + l15;
        int sl = (kk * 4 + l4) ^ (row & 7);
        kf[ni] = *(const bf16x8*)(&Kt[p][row * 128 + sl * 8]);
      }
#pragma unroll
      for (int ni = 0; ni < 4; ++ni)
        s[ni] = MFMA16(kf[ni], qf[kk], s[ni]);
    }

    // ---- scale (+ tail mask j>=cnt)
    if (kv + KVB > cnt) {
#pragma unroll
      for (int ni = 0; ni < 4; ++ni)
#pragma unroll
        for (int r = 0; r < 4; ++r) {
          int j = kv + ni * 16 + l4 * 4 + r;
          s[ni][r] = (j < cnt) ? s[ni][r] * scale : -1e20f;
        }
    } else {
#pragma unroll
      for (int ni = 0; ni < 4; ++ni)
#pragma unroll
        for (int r = 0; r < 4; ++r) s[ni][r] *= scale;
    }

    // ---- online softmax (thread's row q = wq+l15); T13 defer-max
    float vmax = -1e20f;
#pragma unroll
    for (int ni = 0; ni < 4; ++ni)
#pragma unroll
      for (int r = 0; r < 4; ++r) vmax = fmaxf(vmax, s[ni][r]);
    vmax = fmaxf(vmax, __shfl_xor(vmax, 16));
    vmax = fmaxf(vmax, __shfl_xor(vmax, 32));
    bool nd = vmax > mreg + 8.0f;
    float corr = nd ? __expf(mreg - vmax) : 1.0f;
    float mn = nd ? vmax : mreg;
    mreg = mn;
    float rsum = 0.f;
    uint32_t u[4][2];
#pragma unroll
    for (int ni = 0; ni < 4; ++ni) {
      float p0 = __expf(s[ni][0] - mn);
      float p1 = __expf(s[ni][1] - mn);
      float p2 = __expf(s[ni][2] - mn);
      float p3 = __expf(s[ni][3] - mn);
      rsum += (p0 + p1) + (p2 + p3);
      u[ni][0] = pkbf(p0, p1);
      u[ni][1] = pkbf(p2, p3);
    }
    rsum += __shfl_xor(rsum, 16);
    rsum += __shfl_xor(rsum, 32);
    lreg = lreg * corr + rsum;
    if (__any(nd)) {               // rare: rescale o (rows q = wq + l4*4 + r)
#pragma unroll
      for (int r = 0; r < 4; ++r) {
        float cr = __shfl(corr, l4 * 20 + r);
#pragma unroll
        for (int ni = 0; ni < 8; ++ni) o[ni][r] *= cr;
      }
    }

    // ---- P redistribute (in-register) + PV
    const int srcA = l15 + ((l & 16) << 1);   // lane with (b5=own b4, b4=0)
    const int srcB = srcA + 16;
    const bool e5 = (l4 >> 1) != 0;           // own bit5 selects ni parity
#pragma unroll
    for (int kk = 0; kk < 2; ++kk) {
      uint32_t a0 = (uint32_t)__shfl((int)u[kk * 2][0], srcA);
      uint32_t a1 = (uint32_t)__shfl((int)u[kk * 2][1], srcA);
      uint32_t a2 = (uint32_t)__shfl((int)u[kk * 2][0], srcB);
      uint32_t a3 = (uint32_t)__shfl((int)u[kk * 2][1], srcB);
      uint32_t b0 = (uint32_t)__shfl((int)u[kk * 2 + 1][0], srcA);
      uint32_t b1 = (uint32_t)__shfl((int)u[kk * 2 + 1][1], srcA);
      uint32_t b2 = (uint32_t)__shfl((int)u[kk * 2 + 1][0], srcB);
      uint32_t b3 = (uint32_t)__shfl((int)u[kk * 2 + 1][1], srcB);
      u32x4 pw = { e5 ? b0 : a0, e5 ? b1 : a1, e5 ? b2 : a2, e5 ? b3 : a3 };
      bf16x8 pa = __builtin_bit_cast(bf16x8, pw);
      bf16x8 vb[8];
#pragma unroll
      for (int ni = 0; ni < 8; ++ni) {
        int d = ni * 16 + l15;
        int col = (kk * 32 + l4 * 8) ^ ((d & 7) << 3);
        vb[ni] = *(const bf16x8*)(&VT[p][d * KVB + col]);
      }
#pragma unroll
      for (int ni = 0; ni < 8; ++ni)
        o[ni] = MFMA16(pa, vb[ni], o[ni]);
    }

    if (pre) writeV(vr, p ^ 1);    // write next tile's V (waits its loads)
    __syncthreads();
  }

  // ---- epilogue (rows q = wq + l4*4 + r; 1/l held at lane l15=q)
  float inv = 1.f / lreg;
#pragma unroll
  for (int r = 0; r < 4; ++r) {
    float iv = __shfl(inv, l4 * 20 + r);
    long grow = (long)n * L + q0 + wq + l4 * 4 + r;
#pragma unroll
    for (int ni = 0; ni < 8; ++ni)
      Op[grow * E + h * 128 + ni * 16 + l15] = (bf16)(o[ni][r] * iv);
  }
}

// ---------------------------------------------------------------------------
extern "C" void kernel_launch(void* const* d_in, const int* in_sizes, int n_in,
                              void* d_out, int out_size, void* d_ws, size_t ws_size,
                              hipStream_t stream) {
  (void)in_sizes; (void)n_in; (void)out_size; (void)ws_size;
  const float* query = (const float*)d_in[0];
  const float* keys  = (const float*)d_in[1];
  const float* values= (const float*)d_in[2];
  const int*   mask  = (const int*)d_in[3];
  const float* Wq = (const float*)d_in[4];
  const float* Wk = (const float*)d_in[5];
  const float* Wv = (const float*)d_in[6];
  const float* Wo = (const float*)d_in[7];
  const float* bo = (const float*)d_in[8];
  float* out = (float*)d_out;

  const int N = 4, L = 2048, E = 2048;
  const int M = N * L;  // 8192
  const long EE = (long)E * E;
  const long ME = (long)M * E;

  int*  idx  = (int*)d_ws;
  int*  cnts = idx + N * 2048;
  bf16* wslot= (bf16*)((char*)d_ws + 65536);
  bf16* xs   = wslot + EE;
  bf16* qp   = xs + ME;
  bf16* kp   = qp + ME;
  bf16* vp   = kp + ME;

  const int cbw = (int)(EE / 4 / 256);
  const int cba = (int)(ME / 4 / 256);
  const int gbl = (int)(ME / 8 / 256);
  dim3 gg(32, 8);

  mask_compact<<<4, 256, 0, stream>>>(mask, idx, cnts);

  // Q projection
  cvt_bf16<<<cbw, 256, 0, stream>>>(Wq, wslot, EE);
  cvt_bf16<<<cba, 256, 0, stream>>>(query, xs, ME);
  gemm256<0, 0, 0><<<gg, 512, 0, stream>>>(xs, wslot, qp, nullptr, cnts);

  // K projection (gathered/compacted)
  cvt_bf16<<<cbw, 256, 0, stream>>>(Wk, wslot, EE);
  gather_cvt<<<gbl, 256, 0, stream>>>(keys, xs, idx);
  gemm256<1, 0, 0><<<gg, 512, 0, stream>>>(xs, wslot, kp, nullptr, cnts);

  // V projection (gathered/compacted)
  cvt_bf16<<<cbw, 256, 0, stream>>>(Wv, wslot, EE);
  gather_cvt<<<gbl, 256, 0, stream>>>(values, xs, idx);
  gemm256<1, 0, 0><<<gg, 512, 0, stream>>>(xs, wslot, vp, nullptr, cnts);

  // attention over compacted keys (output aliases qp)
  attn_fwd<<<1024, 512, 0, stream>>>(qp, kp, vp, cnts, qp);

  // output projection + bias
  cvt_bf16<<<cbw, 256, 0, stream>>>(Wo, wslot, EE);
  gemm256<0, 1, 1><<<gg, 512, 0, stream>>>(qp, wslot, out, bo, cnts);
}

// Round 6
// 452.047 us; speedup vs baseline: 2.0883x; 1.0591x over previous
//
#include <hip/hip_runtime.h>
#include <stdint.h>

// ---------------------------------------------------------------------------
// MultiHeadAttention: out = softmax(mask((X Wq^T)(X Wk^T)^T * E^-0.5)) (X Wv^T) Wo^T + bo
// N=4, L=2048, E=2048, H=16, D=128.  bf16 MFMA GEMMs, f32 softmax.
// R5 -> R6: attn V-transpose write remapped to bank-conflict FLOOR
// (jg/dg bit-split so write bank-pair index spans all 16 values x4 lanes),
// T5 setprio around attn MFMA clusters, 4 weight cvts fused into one launch,
// xs staging moved into d_out (dead before final GEMM overwrites it).
// Workspace (128MB + 64KB):
//   [0,64KB)      idx (int[4][2048]), cnts (int[8])
//   [64KB,+32MB)  Wqb,Wkb,Wvb,Wob (bf16, 8MB each)
//   [+32MB)       qp  (Q proj; attn output aliases this)
//   [+32MB)       kp  (compacted K proj)
//   [+32MB)       vp  (compacted V proj)
//   xs (bf16 activations) lives in d_out (64MB f32 out >= 32MB bf16 staging).
// ---------------------------------------------------------------------------

typedef __bf16 bf16;
typedef __bf16 bf16x2 __attribute__((ext_vector_type(2)));
typedef __bf16 bf16x4 __attribute__((ext_vector_type(4)));
typedef __bf16 bf16x8 __attribute__((ext_vector_type(8)));
typedef float  f32x4  __attribute__((ext_vector_type(4)));
typedef uint32_t u32x4 __attribute__((ext_vector_type(4)));

#define MFMA16(a, b, c) __builtin_amdgcn_mfma_f32_16x16x32_bf16(a, b, c, 0, 0, 0)

__device__ __forceinline__ void gload_lds16(const void* g, void* s) {
  __builtin_amdgcn_global_load_lds(
      (const __attribute__((address_space(1))) void*)g,
      (__attribute__((address_space(3))) void*)s, 16, 0, 0);
}

__device__ __forceinline__ uint32_t pkbf(float a, float b) {
  return __builtin_bit_cast(uint32_t, (bf16x2){(bf16)a, (bf16)b});
}

// ---------------------------------------------------------------------------
__global__ __launch_bounds__(256) void cvt_bf16(const float* __restrict__ src,
                                                bf16* __restrict__ dst, long n) {
  long i = ((long)blockIdx.x * 256 + threadIdx.x) * 4;
  if (i < n) {
    f32x4 f = *(const f32x4*)(src + i);
    bf16x4 h = { (bf16)f.x, (bf16)f.y, (bf16)f.z, (bf16)f.w };
    *(bf16x4*)(dst + i) = h;
  }
}

// 4 weight conversions in one launch (blockIdx.y selects the matrix).
__global__ __launch_bounds__(256) void cvt4_bf16(const float* __restrict__ s0,
                                                 const float* __restrict__ s1,
                                                 const float* __restrict__ s2,
                                                 const float* __restrict__ s3,
                                                 bf16* __restrict__ d0,
                                                 bf16* __restrict__ d1,
                                                 bf16* __restrict__ d2,
                                                 bf16* __restrict__ d3) {
  int wsel = blockIdx.y;
  const float* src = wsel == 0 ? s0 : wsel == 1 ? s1 : wsel == 2 ? s2 : s3;
  bf16* dst = wsel == 0 ? d0 : wsel == 1 ? d1 : wsel == 2 ? d2 : d3;
  long i = ((long)blockIdx.x * 256 + threadIdx.x) * 4;
  f32x4 f = *(const f32x4*)(src + i);
  bf16x4 h = { (bf16)f.x, (bf16)f.y, (bf16)f.z, (bf16)f.w };
  *(bf16x4*)(dst + i) = h;
}

// Gather rows through compacted idx while converting f32->bf16.
__global__ __launch_bounds__(256) void gather_cvt(const float* __restrict__ src,
                                                  bf16* __restrict__ dst,
                                                  const int* __restrict__ idx) {
  long i = (long)blockIdx.x * 256 + threadIdx.x;  // unit of 8 elements
  int row = (int)(i >> 8);
  int u = (int)(i & 255);
  int n = row >> 11, p = row & 2047;
  long srow = ((long)n << 11) + idx[(n << 11) + p];
  const float* s = src + srow * 2048 + u * 8;
  f32x4 a = *(const f32x4*)s;
  f32x4 b = *(const f32x4*)(s + 4);
  bf16x8 h = { (bf16)a.x, (bf16)a.y, (bf16)a.z, (bf16)a.w,
               (bf16)b.x, (bf16)b.y, (bf16)b.z, (bf16)b.w };
  *(bf16x8*)(dst + (long)row * 2048 + u * 8) = h;
}

// ---------------------------------------------------------------------------
// Per-n compaction of mask==1 indices. grid = 4 x 256.
// ---------------------------------------------------------------------------
__global__ __launch_bounds__(256) void mask_compact(const int* __restrict__ mask,
                                                    int* __restrict__ idx,
                                                    int* __restrict__ cnts) {
  const int n = blockIdx.x;
  const int t = threadIdx.x, l = t & 63, w = t >> 6;
  const int* m = mask + n * 2048;
  __shared__ int wtot[4];
  int f[8], tt = 0;
  const int base = t * 8;
#pragma unroll
  for (int i = 0; i < 8; ++i) { f[i] = (m[base + i] != 0); tt += f[i]; }
  int sc = tt;
#pragma unroll
  for (int d = 1; d < 64; d <<= 1) {
    int v = __shfl_up(sc, d);
    if (l >= d) sc += v;
  }
  if (l == 63) wtot[w] = sc;
  __syncthreads();
  int woff = 0;
#pragma unroll
  for (int i = 0; i < 4; ++i) if (i < w) woff += wtot[i];
  int off = woff + sc - tt;
#pragma unroll
  for (int i = 0; i < 8; ++i)
    if (f[i]) { idx[n * 2048 + off] = base + i; ++off; }
  int total = wtot[0] + wtot[1] + wtot[2] + wtot[3];
  for (int p = total + t; p < 2048; p += 256) idx[n * 2048 + p] = 2047;
  if (t == 0) { cnts[n] = total; cnts[4 + n] = (total + 127) & ~127; }
}

// ---------------------------------------------------------------------------
// 256x256 GEMM (unchanged from R4/R5): counted-vmcnt double-buffered pipeline.
// ---------------------------------------------------------------------------
template <int AEXIT, int OUT_F32, int ADD_BIAS>
__global__ __launch_bounds__(512, 2) void gemm256(const bf16* __restrict__ A,
                                                  const bf16* __restrict__ B,
                                                  void* __restrict__ Cout,
                                                  const float* __restrict__ bias,
                                                  const int* __restrict__ cnts) {
  constexpr int K = 2048, LDC = 2048, NT = 32;
  constexpr int TILE = 256 * 64;
  __shared__ bf16 S[2 * 2 * TILE];
  const int t = threadIdx.x;
  const int l = t & 63, w = t >> 6;
  const int wr = w >> 2, wc = w & 3;
  const int l15 = l & 15, l4 = l >> 4;

  const int Mb = ((blockIdx.x & 7) << 2) + (blockIdx.x >> 3);
  const long tm = (long)Mb * 256;
  const long tn = (long)blockIdx.y * 256;

  if constexpr (AEXIT) {
    int n = (int)(tm >> 11);
    if ((int)(tm & 2047) >= cnts[4 + n]) return;
  }

  const bf16* Ab = A + tm * K;
  const bf16* Bb = B + tn * K;

  auto stage = [&](int T, int p) {
    bf16* sA = S + p * 2 * TILE;
    bf16* sB = sA + TILE;
    const bf16* Ak = Ab + T * 64;
    const bf16* Bk = Bb + T * 64;
#pragma unroll
    for (int i = 0; i < 4; ++i) {
      int u = i * 512 + t;
      int row = u >> 3, slot = u & 7;
      int ss = slot ^ (row & 7);
      gload_lds16(Ak + (long)row * K + ss * 8, sA + u * 8);
    }
#pragma unroll
    for (int i = 0; i < 4; ++i) {
      int u = i * 512 + t;
      int row = u >> 3, slot = u & 7;
      int ss = slot ^ (row & 7);
      gload_lds16(Bk + (long)row * K + ss * 8, sB + u * 8);
    }
  };

  f32x4 acc[8][4];
#pragma unroll
  for (int i = 0; i < 8; ++i)
#pragma unroll
    for (int j = 0; j < 4; ++j) acc[i][j] = (f32x4){0.f, 0.f, 0.f, 0.f};

  stage(0, 0);

  for (int T = 0; T < NT; ++T) {
    const int p = T & 1;
    const bf16* sA = S + p * 2 * TILE;
    const bf16* sB = sA + TILE;

    asm volatile("" ::: "memory");
    __builtin_amdgcn_s_barrier();
    asm volatile("" ::: "memory");
    if (T + 1 < NT) {
      stage(T + 1, p ^ 1);
      asm volatile("s_waitcnt vmcnt(8)" ::: "memory");
    } else {
      asm volatile("s_waitcnt vmcnt(0)" ::: "memory");
    }
    __builtin_amdgcn_s_barrier();
    asm volatile("" ::: "memory");

#pragma unroll
    for (int kk = 0; kk < 2; ++kk) {
      bf16x8 af[8], bf[4];
#pragma unroll
      for (int mi = 0; mi < 8; ++mi) {
        int row = wr * 128 + mi * 16 + l15;
        int slot = (kk * 4 + l4) ^ (row & 7);
        af[mi] = *(const bf16x8*)(sA + row * 64 + slot * 8);
      }
#pragma unroll
      for (int ni = 0; ni < 4; ++ni) {
        int row = wc * 64 + ni * 16 + l15;
        int slot = (kk * 4 + l4) ^ (row & 7);
        bf[ni] = *(const bf16x8*)(sB + row * 64 + slot * 8);
      }
      __builtin_amdgcn_s_setprio(1);
#pragma unroll
      for (int mi = 0; mi < 8; ++mi)
#pragma unroll
        for (int ni = 0; ni < 4; ++ni)
          acc[mi][ni] = MFMA16(af[mi], bf[ni], acc[mi][ni]);
      __builtin_amdgcn_s_setprio(0);
    }
  }

#pragma unroll
  for (int mi = 0; mi < 8; ++mi) {
#pragma unroll
    for (int ni = 0; ni < 4; ++ni) {
      long col = tn + wc * 64 + ni * 16 + l15;
      long row = tm + wr * 128 + mi * 16 + l4 * 4;
#pragma unroll
      for (int r = 0; r < 4; ++r) {
        float v = acc[mi][ni][r];
        if constexpr (OUT_F32) {
          if constexpr (ADD_BIAS) v += bias[col];
          ((float*)Cout)[(row + r) * (long)LDC + col] = v;
        } else {
          ((bf16*)Cout)[(row + r) * (long)LDC + col] = (bf16)v;
        }
      }
    }
  }
}

// ---------------------------------------------------------------------------
// Flash attention over COMPACTED keys. 1024 blocks x 512 threads (8 waves x
// 16 q-rows), XCD-swizzled decode. Double-buffered K/V (issue-early /
// write-late). V-transpose thread mapping chosen for write-bank FLOOR:
//   jg = (l15&1) + 2*l4 + 8*(w&1)   (16 j-groups of 4)
//   dg = (l15>>1) + 8*(w>>1)        (32 d-groups of 4)
// write bank-pair = jg ^ 2*(d&7) spans 16 values x 4 lanes (floor);
// loads stay 64B-segment coalesced; read swizzle col ^= 8*(d&7) unchanged.
// Swapped QK^T; in-register P redistribution; T13 defer-max; T5 setprio.
// ---------------------------------------------------------------------------
__global__ __launch_bounds__(512, 4) void attn_fwd(const bf16* __restrict__ Qp,
                                                   const bf16* __restrict__ Kp,
                                                   const bf16* __restrict__ Vp,
                                                   const int* __restrict__ cnts,
                                                   bf16* __restrict__ Op) {
  constexpr int L = 2048, E = 2048, KVB = 64;
  __shared__ bf16 Kt[2][KVB * 128];   // [j][16 slots of 8], swizzled  16KB x2
  __shared__ bf16 VT[2][128 * KVB];   // [d][j], swizzled              16KB x2
  const int t = threadIdx.x, l = t & 63, w = t >> 6;
  const int l15 = l & 15, l4 = l >> 4;

  const int b = blockIdx.x;
  const int slot = ((b & 7) << 7) + (b >> 3);
  const int q0 = (slot & 15) << 7;
  const int y = slot >> 4;
  const int n = y >> 4, h = y & 15;
  const int wq = w * 16;
  const float scale = 0.022097086912079608f;  // E^-0.5

  const bf16* Qb = Qp + ((long)n * L + q0) * E + h * 128;
  const bf16* Kb = Kp + (long)n * L * E + h * 128;
  const bf16* Vb = Vp + (long)n * L * E + h * 128;
  const int cnt = cnts[n];
  const int ntk = (cnt + 63) >> 6;

  // Q fragments: rows wq+l15 (16 per wave), k-slices l4*8
  bf16x8 qf[4];
#pragma unroll
  for (int kk = 0; kk < 4; ++kk)
    qf[kk] = *(const bf16x8*)(Qb + (long)(wq + l15) * E + kk * 32 + l4 * 8);

  f32x4 o[8];
#pragma unroll
  for (int ni = 0; ni < 8; ++ni) o[ni] = (f32x4){0.f, 0.f, 0.f, 0.f};
  float mreg = -1e20f, lreg = 0.f;

  // V-transpose mapping (write-bank floor; see header comment)
  const int vj0 = ((l15 & 1) + 2 * l4 + 8 * (w & 1)) * 4;   // 4 j's
  const int vd0 = ((l15 >> 1) + 8 * (w >> 1)) * 4;          // 4 d's

  auto stageK = [&](int kv, int pp) {
#pragma unroll
    for (int i = 0; i < 2; ++i) {
      int u = i * 512 + t;
      int row = u >> 4, sl = u & 15;
      gload_lds16(Kb + (long)(kv + row) * E + ((sl ^ (row & 7)) * 8),
                  &Kt[pp][u * 8]);
    }
  };
  auto loadV = [&](int kv, bf16x4* vr) {
#pragma unroll
    for (int r = 0; r < 4; ++r)
      vr[r] = *(const bf16x4*)(Vb + (long)(kv + vj0 + r) * E + vd0);
  };
  auto writeV = [&](const bf16x4* vr, int pp) {
#pragma unroll
    for (int i = 0; i < 4; ++i) {
      int d = vd0 + i;
      bf16x4 pk = { vr[0][i], vr[1][i], vr[2][i], vr[3][i] };
      *(bf16x4*)(&VT[pp][d * KVB + (vj0 ^ ((d & 7) << 3))]) = pk;
    }
  };

  // prologue: tile 0
  bf16x4 vr[4];
  stageK(0, 0);
  loadV(0, vr);
  writeV(vr, 0);
  __syncthreads();

  for (int ti = 0; ti < ntk; ++ti) {
    const int p = ti & 1;
    const int kv = ti << 6;
    const bool pre = (ti + 1) < ntk;
    if (pre) {                      // issue next tile's staging EARLY
      stageK(kv + KVB, p ^ 1);
      loadV(kv + KVB, vr);
    }

    // ---- S^T = K Q^T  (rows j, cols q)
    f32x4 s[4];
#pragma unroll
    for (int ni = 0; ni < 4; ++ni) s[ni] = (f32x4){0.f, 0.f, 0.f, 0.f};
#pragma unroll
    for (int kk = 0; kk < 4; ++kk) {
      bf16x8 kf[4];
#pragma unroll
      for (int ni = 0; ni < 4; ++ni) {
        int row = ni * 16 + l15;
        int sl = (kk * 4 + l4) ^ (row & 7);
        kf[ni] = *(const bf16x8*)(&Kt[p][row * 128 + sl * 8]);
      }
      __builtin_amdgcn_s_setprio(1);
#pragma unroll
      for (int ni = 0; ni < 4; ++ni)
        s[ni] = MFMA16(kf[ni], qf[kk], s[ni]);
      __builtin_amdgcn_s_setprio(0);
    }

    // ---- scale (+ tail mask j>=cnt)
    if (kv + KVB > cnt) {
#pragma unroll
      for (int ni = 0; ni < 4; ++ni)
#pragma unroll
        for (int r = 0; r < 4; ++r) {
          int j = kv + ni * 16 + l4 * 4 + r;
          s[ni][r] = (j < cnt) ? s[ni][r] * scale : -1e20f;
        }
    } else {
#pragma unroll
      for (int ni = 0; ni < 4; ++ni)
#pragma unroll
        for (int r = 0; r < 4; ++r) s[ni][r] *= scale;
    }

    // ---- online softmax (thread's row q = wq+l15); T13 defer-max
    float vmax = -1e20f;
#pragma unroll
    for (int ni = 0; ni < 4; ++ni)
#pragma unroll
      for (int r = 0; r < 4; ++r) vmax = fmaxf(vmax, s[ni][r]);
    vmax = fmaxf(vmax, __shfl_xor(vmax, 16));
    vmax = fmaxf(vmax, __shfl_xor(vmax, 32));
    bool nd = vmax > mreg + 8.0f;
    float corr = nd ? __expf(mreg - vmax) : 1.0f;
    float mn = nd ? vmax : mreg;
    mreg = mn;
    float rsum = 0.f;
    uint32_t u[4][2];
#pragma unroll
    for (int ni = 0; ni < 4; ++ni) {
      float p0 = __expf(s[ni][0] - mn);
      float p1 = __expf(s[ni][1] - mn);
      float p2 = __expf(s[ni][2] - mn);
      float p3 = __expf(s[ni][3] - mn);
      rsum += (p0 + p1) + (p2 + p3);
      u[ni][0] = pkbf(p0, p1);
      u[ni][1] = pkbf(p2, p3);
    }
    rsum += __shfl_xor(rsum, 16);
    rsum += __shfl_xor(rsum, 32);
    lreg = lreg * corr + rsum;
    if (__any(nd)) {               // rare: rescale o (rows q = wq + l4*4 + r)
#pragma unroll
      for (int r = 0; r < 4; ++r) {
        float cr = __shfl(corr, l4 * 20 + r);
#pragma unroll
        for (int ni = 0; ni < 8; ++ni) o[ni][r] *= cr;
      }
    }

    // ---- P redistribute (in-register) + PV
    const int srcA = l15 + ((l & 16) << 1);
    const int srcB = srcA + 16;
    const bool e5 = (l4 >> 1) != 0;
#pragma unroll
    for (int kk = 0; kk < 2; ++kk) {
      uint32_t a0 = (uint32_t)__shfl((int)u[kk * 2][0], srcA);
      uint32_t a1 = (uint32_t)__shfl((int)u[kk * 2][1], srcA);
      uint32_t a2 = (uint32_t)__shfl((int)u[kk * 2][0], srcB);
      uint32_t a3 = (uint32_t)__shfl((int)u[kk * 2][1], srcB);
      uint32_t b0 = (uint32_t)__shfl((int)u[kk * 2 + 1][0], srcA);
      uint32_t b1 = (uint32_t)__shfl((int)u[kk * 2 + 1][1], srcA);
      uint32_t b2 = (uint32_t)__shfl((int)u[kk * 2 + 1][0], srcB);
      uint32_t b3 = (uint32_t)__shfl((int)u[kk * 2 + 1][1], srcB);
      u32x4 pw = { e5 ? b0 : a0, e5 ? b1 : a1, e5 ? b2 : a2, e5 ? b3 : a3 };
      bf16x8 pa = __builtin_bit_cast(bf16x8, pw);
      bf16x8 vb[8];
#pragma unroll
      for (int ni = 0; ni < 8; ++ni) {
        int d = ni * 16 + l15;
        int col = (kk * 32 + l4 * 8) ^ ((d & 7) << 3);
        vb[ni] = *(const bf16x8*)(&VT[p][d * KVB + col]);
      }
      __builtin_amdgcn_s_setprio(1);
#pragma unroll
      for (int ni = 0; ni < 8; ++ni)
        o[ni] = MFMA16(pa, vb[ni], o[ni]);
      __builtin_amdgcn_s_setprio(0);
    }

    if (pre) writeV(vr, p ^ 1);    // write next tile's V (waits its loads)
    __syncthreads();
  }

  // ---- epilogue (rows q = wq + l4*4 + r; 1/l held at lane l15=q)
  float inv = 1.f / lreg;
#pragma unroll
  for (int r = 0; r < 4; ++r) {
    float iv = __shfl(inv, l4 * 20 + r);
    long grow = (long)n * L + q0 + wq + l4 * 4 + r;
#pragma unroll
    for (int ni = 0; ni < 8; ++ni)
      Op[grow * E + h * 128 + ni * 16 + l15] = (bf16)(o[ni][r] * iv);
  }
}

// ---------------------------------------------------------------------------
extern "C" void kernel_launch(void* const* d_in, const int* in_sizes, int n_in,
                              void* d_out, int out_size, void* d_ws, size_t ws_size,
                              hipStream_t stream) {
  (void)in_sizes; (void)n_in; (void)out_size; (void)ws_size;
  const float* query = (const float*)d_in[0];
  const float* keys  = (const float*)d_in[1];
  const float* values= (const float*)d_in[2];
  const int*   mask  = (const int*)d_in[3];
  const float* Wq = (const float*)d_in[4];
  const float* Wk = (const float*)d_in[5];
  const float* Wv = (const float*)d_in[6];
  const float* Wo = (const float*)d_in[7];
  const float* bo = (const float*)d_in[8];
  float* out = (float*)d_out;

  const int N = 4, L = 2048, E = 2048;
  const int M = N * L;  // 8192
  const long EE = (long)E * E;
  const long ME = (long)M * E;

  int*  idx  = (int*)d_ws;
  int*  cnts = idx + N * 2048;
  bf16* Wqb  = (bf16*)((char*)d_ws + 65536);
  bf16* Wkb  = Wqb + EE;
  bf16* Wvb  = Wkb + EE;
  bf16* Wob  = Wvb + EE;
  bf16* qp   = Wob + EE;
  bf16* kp   = qp + ME;
  bf16* vp   = kp + ME;
  bf16* xs   = (bf16*)d_out;   // staging in d_out; fully overwritten by final GEMM

  const int cbw = (int)(EE / 4 / 256);
  const int cba = (int)(ME / 4 / 256);
  const int gbl = (int)(ME / 8 / 256);
  dim3 gg(32, 8);

  mask_compact<<<4, 256, 0, stream>>>(mask, idx, cnts);
  cvt4_bf16<<<dim3(cbw, 4), 256, 0, stream>>>(Wq, Wk, Wv, Wo, Wqb, Wkb, Wvb, Wob);

  // Q projection
  cvt_bf16<<<cba, 256, 0, stream>>>(query, xs, ME);
  gemm256<0, 0, 0><<<gg, 512, 0, stream>>>(xs, Wqb, qp, nullptr, cnts);

  // K projection (gathered/compacted)
  gather_cvt<<<gbl, 256, 0, stream>>>(keys, xs, idx);
  gemm256<1, 0, 0><<<gg, 512, 0, stream>>>(xs, Wkb, kp, nullptr, cnts);

  // V projection (gathered/compacted)
  gather_cvt<<<gbl, 256, 0, stream>>>(values, xs, idx);
  gemm256<1, 0, 0><<<gg, 512, 0, stream>>>(xs, Wvb, vp, nullptr, cnts);

  // attention over compacted keys (output aliases qp)
  attn_fwd<<<1024, 512, 0, stream>>>(qp, kp, vp, cnts, qp);

  // output projection + bias (reads qp, overwrites all of d_out incl. xs)
  gemm256<0, 1, 1><<<gg, 512, 0, stream>>>(qp, Wob, out, bo, cnts);
}